// Round 3
// baseline (819.772 us; speedup 1.0000x reference)
//
#include <hip/hip_runtime.h>
#include <hip/hip_bf16.h>
#include <hip/hip_fp8.h>

#define PI_F 3.14159265358979323846f
#define NBLK 256     // chunk count for count/scatter passes (scan width)
#define BSH 8        // coarse bucket = 256 dst nodes
#define BSZ 256      // nodes per bucket
#define SCAP 10240   // LDS edge staging capacity (mean 8192, +22 sigma)

static inline size_t align256(size_t x) { return (x + 255) & ~size_t(255); }

typedef float v2f __attribute__((ext_vector_type(2)));

// ---------------- atomic-free bucketed CSR build ----------------
// count/scatter: 1024 threads/block (4x occupancy vs 256; they were 1 wave/SIMD).

__global__ void __launch_bounds__(1024) count_kernel(
                             const int* __restrict__ dst, int* __restrict__ C,
                             int E, int CHUNK, int NB2) {
    extern __shared__ int hist[];   // NB2 ints
    for (int i = threadIdx.x; i < NB2; i += 1024) hist[i] = 0;
    __syncthreads();
    int s0 = blockIdx.x * CHUNK, s1 = min(s0 + CHUNK, E);
    for (int e = s0 + threadIdx.x; e < s1; e += 1024)
        atomicAdd(&hist[dst[e] >> BSH], 1);
    __syncthreads();
    for (int i = threadIdx.x; i < NB2; i += 1024)
        C[(size_t)blockIdx.x * NB2 + i] = hist[i];
}

__global__ void scan_blocks_kernel(int* __restrict__ C, int* __restrict__ colsum, int NB2) {
    __shared__ int s[256];
    int k = blockIdx.x;
    int b = threadIdx.x;
    int v = C[(size_t)b * NB2 + k];
    s[b] = v;
    __syncthreads();
    for (int off = 1; off < 256; off <<= 1) {
        int w = (b >= off) ? s[b - off] : 0;
        __syncthreads();
        s[b] += w;
        __syncthreads();
    }
    C[(size_t)b * NB2 + k] = s[b] - v;   // exclusive
    if (b == 255) colsum[k] = s[255];
}

__global__ void scan_totals_kernel(const int* __restrict__ colsum, int* __restrict__ bbase,
                                   int NB2, int E) {
    __shared__ int s[256];
    __shared__ int running;
    if (threadIdx.x == 0) running = 0;
    __syncthreads();
    for (int base = 0; base < NB2; base += 256) {
        int i = base + threadIdx.x;
        int v = (i < NB2) ? colsum[i] : 0;
        s[threadIdx.x] = v;
        __syncthreads();
        for (int off = 1; off < 256; off <<= 1) {
            int w = (threadIdx.x >= (unsigned)off) ? s[threadIdx.x - off] : 0;
            __syncthreads();
            s[threadIdx.x] += w;
            __syncthreads();
        }
        if (i < NB2) bbase[i] = running + s[threadIdx.x] - v;
        __syncthreads();
        if (threadIdx.x == 255) running += s[255];
        __syncthreads();
    }
    if (threadIdx.x == 0) bbase[NB2] = E;
}

__global__ void __launch_bounds__(1024) scatter_kernel(
                               const int* __restrict__ src, const int* __restrict__ dst,
                               const int* __restrict__ C, const int* __restrict__ bbase,
                               unsigned* __restrict__ bkt_data, int E, int CHUNK, int NB2) {
    extern __shared__ int ofs[];   // NB2 ints
    for (int i = threadIdx.x; i < NB2; i += 1024)
        ofs[i] = bbase[i] + C[(size_t)blockIdx.x * NB2 + i];
    __syncthreads();
    int s0 = blockIdx.x * CHUNK, s1 = min(s0 + CHUNK, E);
    for (int e = s0 + threadIdx.x; e < s1; e += 1024) {
        int d = dst[e];
        int p = atomicAdd(&ofs[d >> BSH], 1);   // LDS atomic only
        bkt_data[p] = ((unsigned)(d & (BSZ - 1)) << 17) | (unsigned)src[e];
    }
}

// 512 threads: staging loops at 2x parallelism; scan confined to tid<256
// with barrier-safe masking.
__global__ void __launch_bounds__(512) csr_build_kernel(
                                 const unsigned* __restrict__ bkt_data, const int* __restrict__ bbase,
                                 const float* __restrict__ x,
                                 unsigned* __restrict__ csr, int* __restrict__ e_start,
                                 float* __restrict__ dinv, float* __restrict__ xd,
                                 int N, int NB2) {
    __shared__ unsigned sdata[SCAP];
    __shared__ int hist[256];
    __shared__ int scn[256];
    __shared__ int bump[256];
    int tid = threadIdx.x;
    int b = blockIdx.x;
    int g0 = bbase[b], g1 = bbase[b + 1];
    int cnt = g1 - g0;
    bool fits = (cnt <= SCAP);
    if (tid < 256) hist[tid] = 0;
    __syncthreads();
    for (int i = tid; i < cnt; i += 512) {
        unsigned pk = bkt_data[g0 + i];
        if (fits) sdata[i] = pk;
        atomicAdd(&hist[pk >> 17], 1);
    }
    __syncthreads();
    int orig = (tid < 256) ? hist[tid] : 0;
    if (tid < 256) scn[tid] = orig;
    __syncthreads();
    for (int off = 1; off < 256; off <<= 1) {
        int w = (tid >= off && tid < 256) ? scn[tid - off] : 0;
        __syncthreads();
        if (tid < 256) scn[tid] += w;
        __syncthreads();
    }
    if (tid < 256) {
        int excl = scn[tid] - orig;
        bump[tid] = g0 + excl;
        int node = b * BSZ + tid;
        if (node < N) {
            float dv = rsqrtf((float)(orig + 1));
            dinv[node] = dv;
            xd[node] = x[node] * dv;
            e_start[node] = g0 + excl;
        }
    }
    if (b == NB2 - 1 && tid == 0) e_start[N] = g1;
    __syncthreads();
    for (int i = tid; i < cnt; i += 512) {
        unsigned pk = fits ? sdata[i] : bkt_data[g0 + i];
        int p = atomicAdd(&bump[pk >> 17], 1);
        csr[p] = pk & 0x1FFFFu;
    }
}

// ---------------- GCN layers ----------------
// u rows: per-row-scaled fp8 e4m3 (OCP): u8[node][32] + uscale[node] f32.

// Layer 1 (rank-1): sum_src u1[src][f] = (sum xd[src])*W1[f]; scalar xd gather.
__global__ void __launch_bounds__(256) agg1_kernel(
                            const float* __restrict__ xd, const int* __restrict__ e_start,
                            const unsigned* __restrict__ csr, const float* __restrict__ dinv,
                            const float* __restrict__ W1, const float* __restrict__ b1,
                            const float* __restrict__ W2,
                            unsigned char* __restrict__ u8out, float* __restrict__ uscale, int n) {
    __shared__ float sW2[1024];
    __shared__ float sW1[32], sb1[32];
    for (int i = threadIdx.x; i < 1024; i += 256) sW2[i] = W2[i];
    if (threadIdx.x < 32) { sW1[threadIdx.x] = W1[threadIdx.x]; sb1[threadIdx.x] = b1[threadIdx.x]; }
    __syncthreads();
    int t = blockIdx.x * 256 + threadIdx.x;
    int d = t >> 6;
    int lane = threadIdx.x & 63;
    if (d >= n) return;
    int e0 = e_start[d];
    int cnt = e_start[d + 1] - e0;
    float s = 0.f;
    for (int j = lane; j < cnt; j += 64) s += xd[csr[e0 + j]];
#pragma unroll
    for (int m = 1; m < 64; m <<= 1) s += __shfl_xor(s, m, 64);
    float dv = dinv[d];
    float tt = dv * (s + xd[d]);
    int f = lane & 31, half = lane >> 5;
    float h1 = fmaxf(tt * sW1[f] + sb1[f], 0.f);   // replicated in both halves
    float p = 0.f;
    int k0 = half << 4;
#pragma unroll
    for (int k = 0; k < 16; k++) p += __shfl(h1, k0 + k, 64) * sW2[(k0 + k) * 32 + f];
    p += __shfl_xor(p, 32, 64);
    float outv = dv * p;
    float am = fabsf(outv);
#pragma unroll
    for (int m = 1; m < 32; m <<= 1) am = fmaxf(am, __shfl_xor(am, m, 64));
    float rm = fmaxf(am, 1e-20f);
    float sc = 128.f / rm;
    if (half == 0) {
        __hip_fp8_e4m3 qv(outv * sc);
        u8out[(size_t)d * 32 + f] = (unsigned char)qv.__x;
        if (f == 0) uscale[d] = rm * (1.f / 128.f);
    }
}

// Deep-pipelined neighbor gather: register prefetch of up to 64 edges + two
// fully unrolled 8-group batches (all u8 gathers in flight). Packed v2f
// accumulate (v_pk_fma_f32), per-component order identical to scalar form.
__device__ __forceinline__ void gather_u8(const unsigned char* __restrict__ u8,
                                          const float* __restrict__ uscale,
                                          const unsigned* __restrict__ csr,
                                          int e0, int cnt, int il, int hb, int slot, int q,
                                          v2f& alo, v2f& ahi) {
    int sv0 = 0, sv1 = 0;
    float rs0 = 0.f, rs1 = 0.f;
    if (il < cnt)      sv0 = (int)csr[e0 + il];
    if (32 + il < cnt) sv1 = (int)csr[e0 + 32 + il];
    if (il < cnt)      rs0 = uscale[sv0];
    if (32 + il < cnt) rs1 = uscale[sv1];
#pragma unroll
    for (int it = 0; it < 8; ++it) {
        int i = (it << 2) | slot;
        int s = __shfl(sv0, hb | i, 64);
        float rs = __shfl(rs0, hb | i, 64);
        unsigned w = *(const unsigned*)(u8 + ((size_t)s << 5) + (q << 2));
        v2f lo = __builtin_amdgcn_cvt_pk_f32_fp8(w, false);
        v2f hi = __builtin_amdgcn_cvt_pk_f32_fp8(w, true);
        v2f rs2 = {rs, rs};
        alo += rs2 * lo; ahi += rs2 * hi;
    }
    if (cnt > 32) {
#pragma unroll
        for (int it = 0; it < 8; ++it) {
            int i = (it << 2) | slot;
            int s = __shfl(sv1, hb | i, 64);
            float rs = __shfl(rs1, hb | i, 64);
            unsigned w = *(const unsigned*)(u8 + ((size_t)s << 5) + (q << 2));
            v2f lo = __builtin_amdgcn_cvt_pk_f32_fp8(w, false);
            v2f hi = __builtin_amdgcn_cvt_pk_f32_fp8(w, true);
            v2f rs2 = {rs, rs};
            alo += rs2 * lo; ahi += rs2 * hi;
        }
        if (cnt > 64) {   // vanishingly rare for Poisson(32)
            for (int c = 64; c < cnt; c += 32) {
                int rem = cnt - c; if (rem > 32) rem = 32;
                int sv = 0; float rsv = 0.f;
                if (il < rem) { sv = (int)csr[e0 + c + il]; rsv = uscale[sv]; }
                for (int i = slot; i < rem; i += 4) {
                    int s = __shfl(sv, hb | i, 64);
                    float rs = __shfl(rsv, hb | i, 64);
                    unsigned w = *(const unsigned*)(u8 + ((size_t)s << 5) + (q << 2));
                    v2f lo = __builtin_amdgcn_cvt_pk_f32_fp8(w, false);
                    v2f hi = __builtin_amdgcn_cvt_pk_f32_fp8(w, true);
                    v2f rs2 = {rs, rs};
                    alo += rs2 * lo; ahi += rs2 * hi;
                }
            }
        }
    }
}

// Two nodes per wave: each 32-lane half handles one dst node.
// il = lane&31; slot = il>>3 (4 edge slots), q = il&7 (8 feature quads).
// agg2: out = fp8rows(dinv*(relu(agg)@W))
__global__ void __launch_bounds__(256) agg2_kernel(
                            const unsigned char* __restrict__ u8, const float* __restrict__ uscale,
                            const int* __restrict__ e_start, const unsigned* __restrict__ csr,
                            const float* __restrict__ dinv, const float* __restrict__ bias,
                            const float* __restrict__ W,
                            unsigned char* __restrict__ o8, float* __restrict__ oscale, int n) {
    int t = blockIdx.x * 256 + threadIdx.x;
    int d = t >> 5;                      // one node per 32-lane half
    int lane = threadIdx.x & 63;
    int il = lane & 31;
    int hb = lane & 32;                  // half base for shuffles
    int slot = il >> 3, q = il & 7;
    float4 Wr[8];
#pragma unroll
    for (int j = 0; j < 8; j++) Wr[j] = *(const float4*)(W + (slot * 8 + j) * 32 + q * 4);
    float4 bq = *(const float4*)(bias + q * 4);
    bool act = (d < n);
    int e0 = 0, cnt = 0;
    float dv = 0.f, rs_self = 0.f;
    unsigned wself = 0;
    if (act) {
        e0 = e_start[d]; cnt = e_start[d + 1] - e0;
        dv = dinv[d];
        rs_self = uscale[d];
        wself = *(const unsigned*)(u8 + ((size_t)d << 5) + (q << 2));
    }
    v2f alo = {0.f, 0.f}, ahi = {0.f, 0.f};
    gather_u8(u8, uscale, csr, e0, cnt, il, hb, slot, q, alo, ahi);
    float a0 = alo.x, a1 = alo.y, a2 = ahi.x, a3 = ahi.y;
#pragma unroll
    for (int m = 8; m < 32; m <<= 1) {   // reduce over 4 slots (within half)
        a0 += __shfl_xor(a0, m, 64); a1 += __shfl_xor(a1, m, 64);
        a2 += __shfl_xor(a2, m, 64); a3 += __shfl_xor(a3, m, 64);
    }
    if (act) {
        v2f lo = __builtin_amdgcn_cvt_pk_f32_fp8(wself, false);
        v2f hi = __builtin_amdgcn_cvt_pk_f32_fp8(wself, true);
        a0 += rs_self * lo.x; a1 += rs_self * lo.y; a2 += rs_self * hi.x; a3 += rs_self * hi.y;
    }
    float v0 = fmaxf(dv * a0 + bq.x, 0.f);
    float v1 = fmaxf(dv * a1 + bq.y, 0.f);
    float v2 = fmaxf(dv * a2 + bq.z, 0.f);
    float v3 = fmaxf(dv * a3 + bq.w, 0.f);
    float p0 = 0.f, p1 = 0.f, p2 = 0.f, p3 = 0.f;
#pragma unroll
    for (int j = 0; j < 8; j++) {
        int srcl = hb | (slot << 1) | (j >> 2);
        float vk;
        switch (j & 3) {
            case 0: vk = __shfl(v0, srcl, 64); break;
            case 1: vk = __shfl(v1, srcl, 64); break;
            case 2: vk = __shfl(v2, srcl, 64); break;
            default: vk = __shfl(v3, srcl, 64); break;
        }
        p0 += vk * Wr[j].x; p1 += vk * Wr[j].y; p2 += vk * Wr[j].z; p3 += vk * Wr[j].w;
    }
#pragma unroll
    for (int m = 8; m < 32; m <<= 1) {
        p0 += __shfl_xor(p0, m, 64); p1 += __shfl_xor(p1, m, 64);
        p2 += __shfl_xor(p2, m, 64); p3 += __shfl_xor(p3, m, 64);
    }
    float o0 = dv * p0, o1 = dv * p1, o2 = dv * p2, o3 = dv * p3;
    float am = fmaxf(fmaxf(fabsf(o0), fabsf(o1)), fmaxf(fabsf(o2), fabsf(o3)));
#pragma unroll
    for (int m = 1; m < 32; m <<= 1) am = fmaxf(am, __shfl_xor(am, m, 64));
    float rm = fmaxf(am, 1e-20f);
    float sc = 128.f / rm;
    int u = 0;
    u = __builtin_amdgcn_cvt_pk_fp8_f32(o0 * sc, o1 * sc, u, false);
    u = __builtin_amdgcn_cvt_pk_fp8_f32(o2 * sc, o3 * sc, u, true);
    if (act && slot == 0) {
        *(unsigned*)(o8 + ((size_t)d << 5) + (q << 2)) = (unsigned)u;
        if (q == 0) oscale[d] = rm * (1.f / 128.f);
    }
}

// agg3: h = relu(agg) + fused theta head + fused mean-pool accumulation
// (atomicAdd into gsum/gcnt; hbuf round-trip eliminated).
__global__ void __launch_bounds__(256) agg3_kernel(
                            const unsigned char* __restrict__ u8, const float* __restrict__ uscale,
                            const int* __restrict__ e_start, const unsigned* __restrict__ csr,
                            const float* __restrict__ dinv, const float* __restrict__ bias,
                            const float* __restrict__ Wt1, const float* __restrict__ bt1,
                            const float* __restrict__ Wt2, const float* __restrict__ bt2,
                            const int* __restrict__ batch,
                            float* __restrict__ gsum, float* __restrict__ gcnt,
                            float* __restrict__ theta, int n) {
    int t = blockIdx.x * 256 + threadIdx.x;
    int d = t >> 5;
    int lane = threadIdx.x & 63;
    int il = lane & 31;
    int hb = lane & 32;
    int slot = il >> 3, q = il & 7;
    float4 Wr[8];
#pragma unroll
    for (int j = 0; j < 8; j++) Wr[j] = *(const float4*)(Wt1 + (slot * 8 + j) * 32 + q * 4);
    float4 bq = *(const float4*)(bias + q * 4);
    float4 bt = *(const float4*)(bt1 + q * 4);
    float4 w2 = *(const float4*)(Wt2 + q * 4);
    float bt2v = bt2[0];
    bool act = (d < n);
    int e0 = 0, cnt = 0, g = 0;
    float dv = 0.f, rs_self = 0.f;
    unsigned wself = 0;
    if (act) {
        e0 = e_start[d]; cnt = e_start[d + 1] - e0;
        dv = dinv[d];
        rs_self = uscale[d];
        wself = *(const unsigned*)(u8 + ((size_t)d << 5) + (q << 2));
        g = batch[d];
    }
    v2f alo = {0.f, 0.f}, ahi = {0.f, 0.f};
    gather_u8(u8, uscale, csr, e0, cnt, il, hb, slot, q, alo, ahi);
    float a0 = alo.x, a1 = alo.y, a2 = ahi.x, a3 = ahi.y;
#pragma unroll
    for (int m = 8; m < 32; m <<= 1) {
        a0 += __shfl_xor(a0, m, 64); a1 += __shfl_xor(a1, m, 64);
        a2 += __shfl_xor(a2, m, 64); a3 += __shfl_xor(a3, m, 64);
    }
    if (act) {
        v2f lo = __builtin_amdgcn_cvt_pk_f32_fp8(wself, false);
        v2f hi = __builtin_amdgcn_cvt_pk_f32_fp8(wself, true);
        a0 += rs_self * lo.x; a1 += rs_self * lo.y; a2 += rs_self * hi.x; a3 += rs_self * hi.y;
    }
    float v0 = fmaxf(dv * a0 + bq.x, 0.f);
    float v1 = fmaxf(dv * a1 + bq.y, 0.f);
    float v2 = fmaxf(dv * a2 + bq.z, 0.f);
    float v3 = fmaxf(dv * a3 + bq.w, 0.f);
    if (act && slot == 0) {
        float* gs = gsum + (size_t)g * 32 + (q << 2);
        atomicAdd(gs + 0, v0);
        atomicAdd(gs + 1, v1);
        atomicAdd(gs + 2, v2);
        atomicAdd(gs + 3, v3);
        if (q == 0) atomicAdd(&gcnt[g], 1.f);
    }
    float p0 = 0.f, p1 = 0.f, p2 = 0.f, p3 = 0.f;
#pragma unroll
    for (int j = 0; j < 8; j++) {
        int srcl = hb | (slot << 1) | (j >> 2);
        float vk;
        switch (j & 3) {
            case 0: vk = __shfl(v0, srcl, 64); break;
            case 1: vk = __shfl(v1, srcl, 64); break;
            case 2: vk = __shfl(v2, srcl, 64); break;
            default: vk = __shfl(v3, srcl, 64); break;
        }
        p0 += vk * Wr[j].x; p1 += vk * Wr[j].y; p2 += vk * Wr[j].z; p3 += vk * Wr[j].w;
    }
#pragma unroll
    for (int m = 8; m < 32; m <<= 1) {
        p0 += __shfl_xor(p0, m, 64); p1 += __shfl_xor(p1, m, 64);
        p2 += __shfl_xor(p2, m, 64); p3 += __shfl_xor(p3, m, 64);
    }
    float tl = fmaxf(p0 + bt.x, 0.f) * w2.x + fmaxf(p1 + bt.y, 0.f) * w2.y
             + fmaxf(p2 + bt.z, 0.f) * w2.z + fmaxf(p3 + bt.w, 0.f) * w2.w;
#pragma unroll
    for (int m = 1; m < 8; m <<= 1) tl += __shfl_xor(tl, m, 64);
    if (act && il == 0) theta[d] = PI_F / (1.f + __expf(-(tl + bt2v)));
}

// ---------------- pooled head ----------------

__global__ void bg_kernel(const float* __restrict__ gsum, const float* __restrict__ gcnt,
                          const float* __restrict__ Wg1, const float* __restrict__ bg1,
                          const float* __restrict__ Wg2, const float* __restrict__ bg2,
                          float* __restrict__ out, int G) {
    __shared__ float sW[1024];
    for (int i = threadIdx.x; i < 1024; i += 256) sW[i] = Wg1[i];
    __syncthreads();
    int t = blockIdx.x * 256 + threadIdx.x;
    int g = t >> 5;
    int lane = threadIdx.x & 63;
    int f = lane & 31, base = lane & 32;
    if (g >= G) return;
    float cnt = fmaxf(gcnt[g], 1.f);
    float hv = gsum[g * 32 + f] / cnt;
    float a = bg1[f];
#pragma unroll
    for (int k = 0; k < 32; k++) a += __shfl(hv, base | k, 64) * sW[k * 32 + f];
    a = fmaxf(a, 0.f);
    float p0 = a * Wg2[f * 2 + 0];
    float p1 = a * Wg2[f * 2 + 1];
    for (int m = 1; m < 32; m <<= 1) {
        p0 += __shfl_xor(p0, m, 64);
        p1 += __shfl_xor(p1, m, 64);
    }
    if (f == 0) {
        out[g * 2 + 0] = 2.f * PI_F / (1.f + __expf(-(p0 + bg2[0])));
        out[g * 2 + 1] = 2.f * PI_F / (1.f + __expf(-(p1 + bg2[1])));
    }
}

// ---------------- launch ----------------

extern "C" void kernel_launch(void* const* d_in, const int* in_sizes, int n_in,
                              void* d_out, int out_size, void* d_ws, size_t ws_size,
                              hipStream_t stream) {
    const float* x   = (const float*)d_in[0];
    const int*   ei  = (const int*)d_in[1];
    const int* batch = (const int*)d_in[2];
    const float* W1  = (const float*)d_in[3];
    const float* b1  = (const float*)d_in[4];
    const float* W2  = (const float*)d_in[5];
    const float* b2  = (const float*)d_in[6];
    const float* W3  = (const float*)d_in[7];
    const float* b3  = (const float*)d_in[8];
    const float* Wt1 = (const float*)d_in[9];
    const float* bt1 = (const float*)d_in[10];
    const float* Wt2 = (const float*)d_in[11];
    const float* bt2 = (const float*)d_in[12];
    const float* Wg1 = (const float*)d_in[13];
    const float* bg1 = (const float*)d_in[14];
    const float* Wg2 = (const float*)d_in[15];
    const float* bg2 = (const float*)d_in[16];

    const int N = in_sizes[0];
    const int E = in_sizes[1] / 2;
    const int G = 128;
    const int* src = ei;
    const int* dst = ei + E;
    float* theta_out = (float*)d_out;
    float* bg_out = (float*)d_out + N;

    const int NB2 = (N + BSZ - 1) >> BSH;
    const int CHUNK = (E + NBLK - 1) / NBLK;

    char* w = (char*)d_ws;
    auto alloc = [&](size_t bytes) -> char* { char* p = w; w += align256(bytes); return p; };
    int*      C        = (int*)alloc((size_t)NBLK * NB2 * 4);
    int*      colsum   = (int*)alloc((size_t)NB2 * 4);
    int*      bbase    = (int*)alloc((size_t)(NB2 + 1) * 4);
    unsigned* bkt_data = (unsigned*)alloc((size_t)E * 4);
    unsigned* csr      = (unsigned*)alloc((size_t)E * 4);
    int*      e_start  = (int*)alloc((size_t)(N + 1) * 4);
    float*    dinv     = (float*)alloc((size_t)N * 4);
    float*    xd       = (float*)alloc((size_t)N * 4);
    unsigned char* u2  = (unsigned char*)alloc((size_t)N * 32);
    float*    us2      = (float*)alloc((size_t)N * 4);
    unsigned char* u3  = (unsigned char*)alloc((size_t)N * 32);
    float*    us3      = (float*)alloc((size_t)N * 4);
    float*    gsum     = (float*)alloc((size_t)G * 32 * 4);
    float*    gcnt     = (float*)alloc((size_t)G * 4);

    hipMemsetAsync(gsum, 0, (size_t)G * 32 * 4, stream);
    hipMemsetAsync(gcnt, 0, (size_t)G * 4, stream);

    size_t ldsB = (size_t)NB2 * 4;
    count_kernel<<<NBLK, 1024, ldsB, stream>>>(dst, C, E, CHUNK, NB2);
    scan_blocks_kernel<<<NB2, 256, 0, stream>>>(C, colsum, NB2);
    scan_totals_kernel<<<1, 256, 0, stream>>>(colsum, bbase, NB2, E);
    scatter_kernel<<<NBLK, 1024, ldsB, stream>>>(src, dst, C, bbase, bkt_data, E, CHUNK, NB2);
    csr_build_kernel<<<NB2, 512, 0, stream>>>(bkt_data, bbase, x, csr, e_start, dinv, xd, N, NB2);

    unsigned gridNW = (unsigned)(((size_t)N * 64 + 255) / 256);  // one wave per node (agg1)
    unsigned gridNH = (unsigned)(((size_t)N * 32 + 255) / 256);  // two nodes per wave (agg2/3)

    // layer 1 (rank-1 collapse) -> fused W2 -> u2 (fp8+scale)
    agg1_kernel<<<gridNW, 256, 0, stream>>>(xd, e_start, csr, dinv, W1, b1, W2, u2, us2, N);
    // layer 2 -> fused W3 -> u3 (fp8+scale)
    agg2_kernel<<<gridNH, 256, 0, stream>>>(u2, us2, e_start, csr, dinv, b2, W3, u3, us3, N);
    // layer 3 -> theta head + fused mean-pool accumulation
    agg3_kernel<<<gridNH, 256, 0, stream>>>(u3, us3, e_start, csr, dinv, b3,
                                            Wt1, bt1, Wt2, bt2, batch, gsum, gcnt,
                                            theta_out, N);

    bg_kernel<<<(G * 32 + 255) / 256, 256, 0, stream>>>(gsum, gcnt, Wg1, bg1, Wg2, bg2, bg_out, G);
}

// Round 4
// 386.530 us; speedup vs baseline: 2.1208x; 2.1208x over previous
//
#include <hip/hip_runtime.h>
#include <hip/hip_bf16.h>
#include <hip/hip_fp8.h>

#define PI_F 3.14159265358979323846f
#define NBLK 256     // chunk count for count/scatter passes (scan width)
#define BSH 8        // coarse bucket = 256 dst nodes
#define BSZ 256      // nodes per bucket
#define SCAP 10240   // LDS edge staging capacity (mean 8192, +22 sigma)
#define PBLK 2048    // persistent blocks for pipelined agg2/agg3

static inline size_t align256(size_t x) { return (x + 255) & ~size_t(255); }

typedef float v2f __attribute__((ext_vector_type(2)));

// ---------------- atomic-free bucketed CSR build ----------------

__global__ void __launch_bounds__(1024) count_kernel(
                             const int* __restrict__ dst, int* __restrict__ C,
                             int E, int CHUNK, int NB2) {
    extern __shared__ int hist[];   // NB2 ints
    for (int i = threadIdx.x; i < NB2; i += 1024) hist[i] = 0;
    __syncthreads();
    int s0 = blockIdx.x * CHUNK, s1 = min(s0 + CHUNK, E);
    for (int e = s0 + threadIdx.x; e < s1; e += 1024)
        atomicAdd(&hist[dst[e] >> BSH], 1);
    __syncthreads();
    for (int i = threadIdx.x; i < NB2; i += 1024)
        C[(size_t)blockIdx.x * NB2 + i] = hist[i];
}

__global__ void scan_blocks_kernel(int* __restrict__ C, int* __restrict__ colsum, int NB2) {
    __shared__ int s[256];
    int k = blockIdx.x;
    int b = threadIdx.x;
    int v = C[(size_t)b * NB2 + k];
    s[b] = v;
    __syncthreads();
    for (int off = 1; off < 256; off <<= 1) {
        int w = (b >= off) ? s[b - off] : 0;
        __syncthreads();
        s[b] += w;
        __syncthreads();
    }
    C[(size_t)b * NB2 + k] = s[b] - v;   // exclusive
    if (b == 255) colsum[k] = s[255];
}

__global__ void scan_totals_kernel(const int* __restrict__ colsum, int* __restrict__ bbase,
                                   int NB2, int E) {
    __shared__ int s[256];
    __shared__ int running;
    if (threadIdx.x == 0) running = 0;
    __syncthreads();
    for (int base = 0; base < NB2; base += 256) {
        int i = base + threadIdx.x;
        int v = (i < NB2) ? colsum[i] : 0;
        s[threadIdx.x] = v;
        __syncthreads();
        for (int off = 1; off < 256; off <<= 1) {
            int w = (threadIdx.x >= (unsigned)off) ? s[threadIdx.x - off] : 0;
            __syncthreads();
            s[threadIdx.x] += w;
            __syncthreads();
        }
        if (i < NB2) bbase[i] = running + s[threadIdx.x] - v;
        __syncthreads();
        if (threadIdx.x == 255) running += s[255];
        __syncthreads();
    }
    if (threadIdx.x == 0) bbase[NB2] = E;
}

__global__ void __launch_bounds__(1024) scatter_kernel(
                               const int* __restrict__ src, const int* __restrict__ dst,
                               const int* __restrict__ C, const int* __restrict__ bbase,
                               unsigned* __restrict__ bkt_data, int E, int CHUNK, int NB2) {
    extern __shared__ int ofs[];   // NB2 ints
    for (int i = threadIdx.x; i < NB2; i += 1024)
        ofs[i] = bbase[i] + C[(size_t)blockIdx.x * NB2 + i];
    __syncthreads();
    int s0 = blockIdx.x * CHUNK, s1 = min(s0 + CHUNK, E);
    for (int e = s0 + threadIdx.x; e < s1; e += 1024) {
        int d = dst[e];
        int p = atomicAdd(&ofs[d >> BSH], 1);   // LDS atomic only
        bkt_data[p] = ((unsigned)(d & (BSZ - 1)) << 17) | (unsigned)src[e];
    }
}

__global__ void __launch_bounds__(512) csr_build_kernel(
                                 const unsigned* __restrict__ bkt_data, const int* __restrict__ bbase,
                                 const float* __restrict__ x,
                                 unsigned* __restrict__ csr, int* __restrict__ e_start,
                                 float* __restrict__ dinv, float* __restrict__ xd,
                                 int N, int NB2) {
    __shared__ unsigned sdata[SCAP];
    __shared__ int hist[256];
    __shared__ int scn[256];
    __shared__ int bump[256];
    int tid = threadIdx.x;
    int b = blockIdx.x;
    int g0 = bbase[b], g1 = bbase[b + 1];
    int cnt = g1 - g0;
    bool fits = (cnt <= SCAP);
    if (tid < 256) hist[tid] = 0;
    __syncthreads();
    for (int i = tid; i < cnt; i += 512) {
        unsigned pk = bkt_data[g0 + i];
        if (fits) sdata[i] = pk;
        atomicAdd(&hist[pk >> 17], 1);
    }
    __syncthreads();
    int orig = (tid < 256) ? hist[tid] : 0;
    if (tid < 256) scn[tid] = orig;
    __syncthreads();
    for (int off = 1; off < 256; off <<= 1) {
        int w = (tid >= off && tid < 256) ? scn[tid - off] : 0;
        __syncthreads();
        if (tid < 256) scn[tid] += w;
        __syncthreads();
    }
    if (tid < 256) {
        int excl = scn[tid] - orig;
        bump[tid] = g0 + excl;
        int node = b * BSZ + tid;
        if (node < N) {
            float dv = rsqrtf((float)(orig + 1));
            dinv[node] = dv;
            xd[node] = x[node] * dv;
            e_start[node] = g0 + excl;
        }
    }
    if (b == NB2 - 1 && tid == 0) e_start[N] = g1;
    __syncthreads();
    for (int i = tid; i < cnt; i += 512) {
        unsigned pk = fits ? sdata[i] : bkt_data[g0 + i];
        int p = atomicAdd(&bump[pk >> 17], 1);
        csr[p] = pk & 0x1FFFFu;
    }
}

// ---------------- GCN layers ----------------
// u rows: per-row-scaled fp8 e4m3 (OCP): u8[node][32] + uscale[node] f32.

// Layer 1 (rank-1): sum_src u1[src][f] = (sum xd[src])*W1[f]; scalar xd gather.
__global__ void __launch_bounds__(256) agg1_kernel(
                            const float* __restrict__ xd, const int* __restrict__ e_start,
                            const unsigned* __restrict__ csr, const float* __restrict__ dinv,
                            const float* __restrict__ W1, const float* __restrict__ b1,
                            const float* __restrict__ W2,
                            unsigned char* __restrict__ u8out, float* __restrict__ uscale, int n) {
    __shared__ float sW2[1024];
    __shared__ float sW1[32], sb1[32];
    for (int i = threadIdx.x; i < 1024; i += 256) sW2[i] = W2[i];
    if (threadIdx.x < 32) { sW1[threadIdx.x] = W1[threadIdx.x]; sb1[threadIdx.x] = b1[threadIdx.x]; }
    __syncthreads();
    int t = blockIdx.x * 256 + threadIdx.x;
    int d = t >> 6;
    int lane = threadIdx.x & 63;
    if (d >= n) return;
    int e0 = e_start[d];
    int cnt = e_start[d + 1] - e0;
    float s = 0.f;
    for (int j = lane; j < cnt; j += 64) s += xd[csr[e0 + j]];
#pragma unroll
    for (int m = 1; m < 64; m <<= 1) s += __shfl_xor(s, m, 64);
    float dv = dinv[d];
    float tt = dv * (s + xd[d]);
    int f = lane & 31, half = lane >> 5;
    float h1 = fmaxf(tt * sW1[f] + sb1[f], 0.f);   // replicated in both halves
    float p = 0.f;
    int k0 = half << 4;
#pragma unroll
    for (int k = 0; k < 16; k++) p += __shfl(h1, k0 + k, 64) * sW2[(k0 + k) * 32 + f];
    p += __shfl_xor(p, 32, 64);
    float outv = dv * p;
    float am = fabsf(outv);
#pragma unroll
    for (int m = 1; m < 32; m <<= 1) am = fmaxf(am, __shfl_xor(am, m, 64));
    float rm = fmaxf(am, 1e-20f);
    float sc = 128.f / rm;
    if (half == 0) {
        __hip_fp8_e4m3 qv(outv * sc);
        u8out[(size_t)d * 32 + f] = (unsigned char)qv.__x;
        if (f == 0) uscale[d] = rm * (1.f / 128.f);
    }
}

// ---- pipeline stage helpers (3-stage cross-node software pipeline) ----

__device__ __forceinline__ void epair(const int* __restrict__ e_start, int d, bool act,
                                      int& x, int& y) {
    int dd = act ? d : 0;
    x = e_start[dd];
    y = e_start[dd + 1];
}

__device__ __forceinline__ void csr_stage(const unsigned* __restrict__ csr,
                                          int e0, int cnt, int il, int& sv0, int& sv1) {
    sv0 = 0; sv1 = 0;
    if (il < cnt)      sv0 = (int)csr[e0 + il];
    if (32 + il < cnt) sv1 = (int)csr[e0 + 32 + il];
}

__device__ __forceinline__ void full_stage(const unsigned char* __restrict__ u8,
                                           const float* __restrict__ uscale,
                                           const float* __restrict__ dinv,
                                           int d, bool act, int cnt, int sv0, int sv1,
                                           int il, int q,
                                           float& rs0, float& rs1, float& dv, float& rss,
                                           unsigned& ws) {
    rs0 = (il < cnt) ? uscale[sv0] : 0.f;
    rs1 = (32 + il < cnt) ? uscale[sv1] : 0.f;
    int dd = act ? d : 0;
    dv = dinv[dd];
    rss = uscale[dd];
    ws = *(const unsigned*)(u8 + ((size_t)dd << 5) + (q << 2));
}

// gather + slot-reduce + self-row add; accumulation order identical to round-2.
__device__ __forceinline__ void gather_core(
        const unsigned char* __restrict__ u8, const float* __restrict__ uscale,
        const unsigned* __restrict__ csr,
        int e0, int cnt, int sv0, int sv1, float rs0, float rs1,
        float rs_self, unsigned wself,
        int il, int hb, int slot, int q,
        float& a0o, float& a1o, float& a2o, float& a3o) {
    v2f alo = {0.f, 0.f}, ahi = {0.f, 0.f};
#pragma unroll
    for (int it = 0; it < 8; ++it) {
        int i = (it << 2) | slot;
        int s = __shfl(sv0, hb | i, 64);
        float rs = __shfl(rs0, hb | i, 64);
        unsigned w = *(const unsigned*)(u8 + ((size_t)s << 5) + (q << 2));
        v2f lo = __builtin_amdgcn_cvt_pk_f32_fp8(w, false);
        v2f hi = __builtin_amdgcn_cvt_pk_f32_fp8(w, true);
        v2f rs2 = {rs, rs};
        alo += rs2 * lo; ahi += rs2 * hi;
    }
    if (cnt > 32) {
#pragma unroll
        for (int it = 0; it < 8; ++it) {
            int i = (it << 2) | slot;
            int s = __shfl(sv1, hb | i, 64);
            float rs = __shfl(rs1, hb | i, 64);
            unsigned w = *(const unsigned*)(u8 + ((size_t)s << 5) + (q << 2));
            v2f lo = __builtin_amdgcn_cvt_pk_f32_fp8(w, false);
            v2f hi = __builtin_amdgcn_cvt_pk_f32_fp8(w, true);
            v2f rs2 = {rs, rs};
            alo += rs2 * lo; ahi += rs2 * hi;
        }
        if (cnt > 64) {   // vanishingly rare for Poisson(32)
            for (int c = 64; c < cnt; c += 32) {
                int rem = cnt - c; if (rem > 32) rem = 32;
                int sv = 0; float rsv = 0.f;
                if (il < rem) { sv = (int)csr[e0 + c + il]; rsv = uscale[sv]; }
                for (int i = slot; i < rem; i += 4) {
                    int s = __shfl(sv, hb | i, 64);
                    float rs = __shfl(rsv, hb | i, 64);
                    unsigned w = *(const unsigned*)(u8 + ((size_t)s << 5) + (q << 2));
                    v2f lo = __builtin_amdgcn_cvt_pk_f32_fp8(w, false);
                    v2f hi = __builtin_amdgcn_cvt_pk_f32_fp8(w, true);
                    v2f rs2 = {rs, rs};
                    alo += rs2 * lo; ahi += rs2 * hi;
                }
            }
        }
    }
    float a0 = alo.x, a1 = alo.y, a2 = ahi.x, a3 = ahi.y;
#pragma unroll
    for (int m = 8; m < 32; m <<= 1) {   // reduce over 4 slots (within half)
        a0 += __shfl_xor(a0, m, 64); a1 += __shfl_xor(a1, m, 64);
        a2 += __shfl_xor(a2, m, 64); a3 += __shfl_xor(a3, m, 64);
    }
    v2f lo = __builtin_amdgcn_cvt_pk_f32_fp8(wself, false);
    v2f hi = __builtin_amdgcn_cvt_pk_f32_fp8(wself, true);
    a0 += rs_self * lo.x; a1 += rs_self * lo.y; a2 += rs_self * hi.x; a3 += rs_self * hi.y;
    a0o = a0; a1o = a1; a2o = a2; a3o = a3;
}

// agg2: persistent half-waves, 3-stage cross-node pipeline.
// Stage A: fully prefetched (compute now); B: csr in flight; C: e_start pair in flight.
__global__ void __launch_bounds__(256) agg2_kernel(
                            const unsigned char* __restrict__ u8, const float* __restrict__ uscale,
                            const int* __restrict__ e_start, const unsigned* __restrict__ csr,
                            const float* __restrict__ dinv, const float* __restrict__ bias,
                            const float* __restrict__ W,
                            unsigned char* __restrict__ o8, float* __restrict__ oscale, int n) {
    int halfid = (blockIdx.x << 3) + (threadIdx.x >> 5);
    int stride = gridDim.x << 3;
    int lane = threadIdx.x & 63;
    int il = lane & 31;
    int hb = lane & 32;
    int slot = il >> 3, q = il & 7;
    float4 bq = *(const float4*)(bias + q * 4);

    int dA = halfid;           bool aA = (dA < n);
    int dB = dA + stride;      bool aB = (dB < n);
    int dC = dB + stride;      bool aC = (dC < n);
    int e0A, e1A; epair(e_start, dA, aA, e0A, e1A);
    int e0B, e1B; epair(e_start, dB, aB, e0B, e1B);
    int e0C, e1C; epair(e_start, dC, aC, e0C, e1C);
    int cntA = aA ? (e1A - e0A) : 0;
    int svA0, svA1; csr_stage(csr, e0A, cntA, il, svA0, svA1);
    int cntB = aB ? (e1B - e0B) : 0;
    int svB0, svB1; csr_stage(csr, e0B, cntB, il, svB0, svB1);
    float rsA0, rsA1, dvA, rssA; unsigned wsA;
    full_stage(u8, uscale, dinv, dA, aA, cntA, svA0, svA1, il, q, rsA0, rsA1, dvA, rssA, wsA);

    while (aA) {
        // issue next-node loads first: they land during compute(A)
        float rsB0, rsB1, dvB, rssB; unsigned wsB;
        full_stage(u8, uscale, dinv, dB, aB, cntB, svB0, svB1, il, q, rsB0, rsB1, dvB, rssB, wsB);
        int cntC = aC ? (e1C - e0C) : 0;
        int svC0, svC1; csr_stage(csr, e0C, cntC, il, svC0, svC1);
        int dD = dC + stride; bool aD = (dD < n);
        int e0D, e1D; epair(e_start, dD, aD, e0D, e1D);

        // ---- compute node A ----
        float a0, a1, a2, a3;
        gather_core(u8, uscale, csr, e0A, cntA, svA0, svA1, rsA0, rsA1,
                    rssA, wsA, il, hb, slot, q, a0, a1, a2, a3);
        float v0 = fmaxf(dvA * a0 + bq.x, 0.f);
        float v1 = fmaxf(dvA * a1 + bq.y, 0.f);
        float v2 = fmaxf(dvA * a2 + bq.z, 0.f);
        float v3 = fmaxf(dvA * a3 + bq.w, 0.f);
        float4 Wr[8];
#pragma unroll
        for (int j = 0; j < 8; j++) Wr[j] = *(const float4*)(W + (slot * 8 + j) * 32 + q * 4);
        float p0 = 0.f, p1 = 0.f, p2 = 0.f, p3 = 0.f;
#pragma unroll
        for (int j = 0; j < 8; j++) {
            int srcl = hb | (slot << 1) | (j >> 2);
            float vk;
            switch (j & 3) {
                case 0: vk = __shfl(v0, srcl, 64); break;
                case 1: vk = __shfl(v1, srcl, 64); break;
                case 2: vk = __shfl(v2, srcl, 64); break;
                default: vk = __shfl(v3, srcl, 64); break;
            }
            p0 += vk * Wr[j].x; p1 += vk * Wr[j].y; p2 += vk * Wr[j].z; p3 += vk * Wr[j].w;
        }
#pragma unroll
        for (int m = 8; m < 32; m <<= 1) {
            p0 += __shfl_xor(p0, m, 64); p1 += __shfl_xor(p1, m, 64);
            p2 += __shfl_xor(p2, m, 64); p3 += __shfl_xor(p3, m, 64);
        }
        float o0 = dvA * p0, o1 = dvA * p1, o2 = dvA * p2, o3 = dvA * p3;
        float am = fmaxf(fmaxf(fabsf(o0), fabsf(o1)), fmaxf(fabsf(o2), fabsf(o3)));
#pragma unroll
        for (int m = 1; m < 32; m <<= 1) am = fmaxf(am, __shfl_xor(am, m, 64));
        float rm = fmaxf(am, 1e-20f);
        float sc = 128.f / rm;
        int u = 0;
        u = __builtin_amdgcn_cvt_pk_fp8_f32(o0 * sc, o1 * sc, u, false);
        u = __builtin_amdgcn_cvt_pk_fp8_f32(o2 * sc, o3 * sc, u, true);
        if (slot == 0) {
            *(unsigned*)(o8 + ((size_t)dA << 5) + (q << 2)) = (unsigned)u;
            if (q == 0) oscale[dA] = rm * (1.f / 128.f);
        }

        // rotate pipeline
        dA = dB; aA = aB; e0A = e0B; cntA = cntB; svA0 = svB0; svA1 = svB1;
        rsA0 = rsB0; rsA1 = rsB1; dvA = dvB; rssA = rssB; wsA = wsB;
        dB = dC; aB = aC; e0B = e0C; cntB = cntC; svB0 = svC0; svB1 = svC1;
        dC = dD; aC = aD; e0C = e0D; e1C = e1D;
    }
}

// agg3: same pipeline; epilogue = hbuf write + theta head (round-2 semantics).
__global__ void __launch_bounds__(256) agg3_kernel(
                            const unsigned char* __restrict__ u8, const float* __restrict__ uscale,
                            const int* __restrict__ e_start, const unsigned* __restrict__ csr,
                            const float* __restrict__ dinv, const float* __restrict__ bias,
                            const float* __restrict__ Wt1, const float* __restrict__ bt1,
                            const float* __restrict__ Wt2, const float* __restrict__ bt2,
                            float* __restrict__ hout, float* __restrict__ theta, int n) {
    int halfid = (blockIdx.x << 3) + (threadIdx.x >> 5);
    int stride = gridDim.x << 3;
    int lane = threadIdx.x & 63;
    int il = lane & 31;
    int hb = lane & 32;
    int slot = il >> 3, q = il & 7;
    float4 bq = *(const float4*)(bias + q * 4);
    float4 bt = *(const float4*)(bt1 + q * 4);
    float4 w2 = *(const float4*)(Wt2 + q * 4);
    float bt2v = bt2[0];

    int dA = halfid;           bool aA = (dA < n);
    int dB = dA + stride;      bool aB = (dB < n);
    int dC = dB + stride;      bool aC = (dC < n);
    int e0A, e1A; epair(e_start, dA, aA, e0A, e1A);
    int e0B, e1B; epair(e_start, dB, aB, e0B, e1B);
    int e0C, e1C; epair(e_start, dC, aC, e0C, e1C);
    int cntA = aA ? (e1A - e0A) : 0;
    int svA0, svA1; csr_stage(csr, e0A, cntA, il, svA0, svA1);
    int cntB = aB ? (e1B - e0B) : 0;
    int svB0, svB1; csr_stage(csr, e0B, cntB, il, svB0, svB1);
    float rsA0, rsA1, dvA, rssA; unsigned wsA;
    full_stage(u8, uscale, dinv, dA, aA, cntA, svA0, svA1, il, q, rsA0, rsA1, dvA, rssA, wsA);

    while (aA) {
        float rsB0, rsB1, dvB, rssB; unsigned wsB;
        full_stage(u8, uscale, dinv, dB, aB, cntB, svB0, svB1, il, q, rsB0, rsB1, dvB, rssB, wsB);
        int cntC = aC ? (e1C - e0C) : 0;
        int svC0, svC1; csr_stage(csr, e0C, cntC, il, svC0, svC1);
        int dD = dC + stride; bool aD = (dD < n);
        int e0D, e1D; epair(e_start, dD, aD, e0D, e1D);

        // ---- compute node A ----
        float a0, a1, a2, a3;
        gather_core(u8, uscale, csr, e0A, cntA, svA0, svA1, rsA0, rsA1,
                    rssA, wsA, il, hb, slot, q, a0, a1, a2, a3);
        float v0 = fmaxf(dvA * a0 + bq.x, 0.f);
        float v1 = fmaxf(dvA * a1 + bq.y, 0.f);
        float v2 = fmaxf(dvA * a2 + bq.z, 0.f);
        float v3 = fmaxf(dvA * a3 + bq.w, 0.f);
        if (slot == 0) *(float4*)(hout + ((size_t)dA << 5) + (q << 2)) = make_float4(v0, v1, v2, v3);
        float4 Wr[8];
#pragma unroll
        for (int j = 0; j < 8; j++) Wr[j] = *(const float4*)(Wt1 + (slot * 8 + j) * 32 + q * 4);
        float p0 = 0.f, p1 = 0.f, p2 = 0.f, p3 = 0.f;
#pragma unroll
        for (int j = 0; j < 8; j++) {
            int srcl = hb | (slot << 1) | (j >> 2);
            float vk;
            switch (j & 3) {
                case 0: vk = __shfl(v0, srcl, 64); break;
                case 1: vk = __shfl(v1, srcl, 64); break;
                case 2: vk = __shfl(v2, srcl, 64); break;
                default: vk = __shfl(v3, srcl, 64); break;
            }
            p0 += vk * Wr[j].x; p1 += vk * Wr[j].y; p2 += vk * Wr[j].z; p3 += vk * Wr[j].w;
        }
#pragma unroll
        for (int m = 8; m < 32; m <<= 1) {
            p0 += __shfl_xor(p0, m, 64); p1 += __shfl_xor(p1, m, 64);
            p2 += __shfl_xor(p2, m, 64); p3 += __shfl_xor(p3, m, 64);
        }
        float tl = fmaxf(p0 + bt.x, 0.f) * w2.x + fmaxf(p1 + bt.y, 0.f) * w2.y
                 + fmaxf(p2 + bt.z, 0.f) * w2.z + fmaxf(p3 + bt.w, 0.f) * w2.w;
#pragma unroll
        for (int m = 1; m < 8; m <<= 1) tl += __shfl_xor(tl, m, 64);
        if (il == 0) theta[dA] = PI_F / (1.f + __expf(-(tl + bt2v)));

        // rotate pipeline
        dA = dB; aA = aB; e0A = e0B; cntA = cntB; svA0 = svB0; svA1 = svB1;
        rsA0 = rsB0; rsA1 = rsB1; dvA = dvB; rssA = rssB; wsA = wsB;
        dB = dC; aB = aC; e0B = e0C; cntB = cntC; svB0 = svC0; svB1 = svC1;
        dC = dD; aC = aD; e0C = e0D; e1C = e1D;
    }
}

// ---------------- heads ----------------

__global__ void pool_kernel(const float* __restrict__ h, const int* __restrict__ batch,
                            float* __restrict__ gsum, float* __restrict__ gcnt, int n) {
    int f = threadIdx.x & 31;
    int sub = threadIdx.x >> 5;
    int start = blockIdx.x * 1024 + sub * 128;
    int end = min(start + 128, n);
    if (start >= end) return;
    int curg = batch[start];
    float acc = 0.f;
    int cnt = 0;
    for (int i = start; i < end; i++) {
        int g = batch[i];
        if (g != curg) {
            atomicAdd(&gsum[curg * 32 + f], acc);
            if (f == 0) atomicAdd(&gcnt[curg], (float)cnt);
            acc = 0.f; cnt = 0; curg = g;
        }
        acc += h[i * 32 + f];
        cnt++;
    }
    atomicAdd(&gsum[curg * 32 + f], acc);
    if (f == 0) atomicAdd(&gcnt[curg], (float)cnt);
}

__global__ void bg_kernel(const float* __restrict__ gsum, const float* __restrict__ gcnt,
                          const float* __restrict__ Wg1, const float* __restrict__ bg1,
                          const float* __restrict__ Wg2, const float* __restrict__ bg2,
                          float* __restrict__ out, int G) {
    __shared__ float sW[1024];
    for (int i = threadIdx.x; i < 1024; i += 256) sW[i] = Wg1[i];
    __syncthreads();
    int t = blockIdx.x * 256 + threadIdx.x;
    int g = t >> 5;
    int lane = threadIdx.x & 63;
    int f = lane & 31, base = lane & 32;
    if (g >= G) return;
    float cnt = fmaxf(gcnt[g], 1.f);
    float hv = gsum[g * 32 + f] / cnt;
    float a = bg1[f];
#pragma unroll
    for (int k = 0; k < 32; k++) a += __shfl(hv, base | k, 64) * sW[k * 32 + f];
    a = fmaxf(a, 0.f);
    float p0 = a * Wg2[f * 2 + 0];
    float p1 = a * Wg2[f * 2 + 1];
    for (int m = 1; m < 32; m <<= 1) {
        p0 += __shfl_xor(p0, m, 64);
        p1 += __shfl_xor(p1, m, 64);
    }
    if (f == 0) {
        out[g * 2 + 0] = 2.f * PI_F / (1.f + __expf(-(p0 + bg2[0])));
        out[g * 2 + 1] = 2.f * PI_F / (1.f + __expf(-(p1 + bg2[1])));
    }
}

// ---------------- launch ----------------

extern "C" void kernel_launch(void* const* d_in, const int* in_sizes, int n_in,
                              void* d_out, int out_size, void* d_ws, size_t ws_size,
                              hipStream_t stream) {
    const float* x   = (const float*)d_in[0];
    const int*   ei  = (const int*)d_in[1];
    const int* batch = (const int*)d_in[2];
    const float* W1  = (const float*)d_in[3];
    const float* b1  = (const float*)d_in[4];
    const float* W2  = (const float*)d_in[5];
    const float* b2  = (const float*)d_in[6];
    const float* W3  = (const float*)d_in[7];
    const float* b3  = (const float*)d_in[8];
    const float* Wt1 = (const float*)d_in[9];
    const float* bt1 = (const float*)d_in[10];
    const float* Wt2 = (const float*)d_in[11];
    const float* bt2 = (const float*)d_in[12];
    const float* Wg1 = (const float*)d_in[13];
    const float* bg1 = (const float*)d_in[14];
    const float* Wg2 = (const float*)d_in[15];
    const float* bg2 = (const float*)d_in[16];

    const int N = in_sizes[0];
    const int E = in_sizes[1] / 2;
    const int G = 128;
    const int* src = ei;
    const int* dst = ei + E;
    float* theta_out = (float*)d_out;
    float* bg_out = (float*)d_out + N;

    const int NB2 = (N + BSZ - 1) >> BSH;
    const int CHUNK = (E + NBLK - 1) / NBLK;

    char* w = (char*)d_ws;
    auto alloc = [&](size_t bytes) -> char* { char* p = w; w += align256(bytes); return p; };
    int*      C        = (int*)alloc((size_t)NBLK * NB2 * 4);
    int*      colsum   = (int*)alloc((size_t)NB2 * 4);
    int*      bbase    = (int*)alloc((size_t)(NB2 + 1) * 4);
    unsigned* bkt_data = (unsigned*)alloc((size_t)E * 4);
    unsigned* csr      = (unsigned*)alloc((size_t)E * 4);
    int*      e_start  = (int*)alloc((size_t)(N + 1) * 4);
    float*    dinv     = (float*)alloc((size_t)N * 4);
    float*    xd       = (float*)alloc((size_t)N * 4);
    unsigned char* u2  = (unsigned char*)alloc((size_t)N * 32);
    float*    us2      = (float*)alloc((size_t)N * 4);
    unsigned char* u3  = (unsigned char*)alloc((size_t)N * 32);
    float*    us3      = (float*)alloc((size_t)N * 4);
    float*    hbuf     = (float*)alloc((size_t)N * 32 * 4);
    float*    gsum     = (float*)alloc((size_t)G * 32 * 4);
    float*    gcnt     = (float*)alloc((size_t)G * 4);

    hipMemsetAsync(gsum, 0, (size_t)G * 32 * 4, stream);
    hipMemsetAsync(gcnt, 0, (size_t)G * 4, stream);

    size_t ldsB = (size_t)NB2 * 4;
    count_kernel<<<NBLK, 1024, ldsB, stream>>>(dst, C, E, CHUNK, NB2);
    scan_blocks_kernel<<<NB2, 256, 0, stream>>>(C, colsum, NB2);
    scan_totals_kernel<<<1, 256, 0, stream>>>(colsum, bbase, NB2, E);
    scatter_kernel<<<NBLK, 1024, ldsB, stream>>>(src, dst, C, bbase, bkt_data, E, CHUNK, NB2);
    csr_build_kernel<<<NB2, 512, 0, stream>>>(bkt_data, bbase, x, csr, e_start, dinv, xd, N, NB2);

    unsigned gridNW = (unsigned)(((size_t)N * 64 + 255) / 256);  // one wave per node (agg1)

    // layer 1 (rank-1 collapse) -> fused W2 -> u2 (fp8+scale)
    agg1_kernel<<<gridNW, 256, 0, stream>>>(xd, e_start, csr, dinv, W1, b1, W2, u2, us2, N);
    // layer 2 -> fused W3 -> u3 (fp8+scale); persistent pipelined
    agg2_kernel<<<PBLK, 256, 0, stream>>>(u2, us2, e_start, csr, dinv, b2, W3, u3, us3, N);
    // layer 3 -> h (fp32) + fused theta head; persistent pipelined
    agg3_kernel<<<PBLK, 256, 0, stream>>>(u3, us3, e_start, csr, dinv, b3,
                                          Wt1, bt1, Wt2, bt2, hbuf, theta_out, N);

    // pooled head
    pool_kernel<<<(N + 1023) / 1024, 256, 0, stream>>>(hbuf, batch, gsum, gcnt, N);
    bg_kernel<<<(G * 32 + 255) / 256, 256, 0, stream>>>(gsum, gcnt, Wg1, bg1, Wg2, bg2, bg_out, G);
}

// Round 5
// 335.592 us; speedup vs baseline: 2.4428x; 1.1518x over previous
//
#include <hip/hip_runtime.h>
#include <hip/hip_bf16.h>

#define PI_F 3.14159265358979323846f
#define NBLK 256     // chunk count for count/scatter passes (scan width)
#define BSH 8        // coarse bucket = 256 dst nodes
#define BSZ 256      // nodes per bucket
#define SCAP 10240   // LDS edge staging capacity (mean 8192, +22 sigma)

static inline size_t align256(size_t x) { return (x + 255) & ~size_t(255); }

// bf16 helpers (bit tricks; round-to-nearest via +0x8000)
__device__ __forceinline__ float bflo(unsigned w) { return __uint_as_float(w << 16); }
__device__ __forceinline__ float bfhi(unsigned w) { return __uint_as_float(w & 0xFFFF0000u); }
__device__ __forceinline__ unsigned bfpack(float a, float b) {
    unsigned lo = (__float_as_uint(a) + 0x8000u) >> 16;
    unsigned hi = (__float_as_uint(b) + 0x8000u) & 0xFFFF0000u;
    return lo | hi;
}

#define BF_ACC8(base, q) \
    acc[(base)+0] += bflo((q).x); acc[(base)+1] += bfhi((q).x); \
    acc[(base)+2] += bflo((q).y); acc[(base)+3] += bfhi((q).y); \
    acc[(base)+4] += bflo((q).z); acc[(base)+5] += bfhi((q).z); \
    acc[(base)+6] += bflo((q).w); acc[(base)+7] += bfhi((q).w);

// ---------------- atomic-free bucketed CSR build ----------------

__global__ void __launch_bounds__(1024) count_kernel(
                             const int* __restrict__ dst, int* __restrict__ C,
                             int E, int CHUNK, int NB2) {
    extern __shared__ int hist[];   // NB2 ints
    for (int i = threadIdx.x; i < NB2; i += 1024) hist[i] = 0;
    __syncthreads();
    int s0 = blockIdx.x * CHUNK, s1 = min(s0 + CHUNK, E);
    for (int e = s0 + threadIdx.x; e < s1; e += 1024)
        atomicAdd(&hist[dst[e] >> BSH], 1);
    __syncthreads();
    for (int i = threadIdx.x; i < NB2; i += 1024)
        C[(size_t)blockIdx.x * NB2 + i] = hist[i];
}

__global__ void scan_blocks_kernel(int* __restrict__ C, int* __restrict__ colsum, int NB2) {
    __shared__ int s[256];
    int k = blockIdx.x;
    int b = threadIdx.x;
    int v = C[(size_t)b * NB2 + k];
    s[b] = v;
    __syncthreads();
    for (int off = 1; off < 256; off <<= 1) {
        int w = (b >= off) ? s[b - off] : 0;
        __syncthreads();
        s[b] += w;
        __syncthreads();
    }
    C[(size_t)b * NB2 + k] = s[b] - v;   // exclusive
    if (b == 255) colsum[k] = s[255];
}

__global__ void scan_totals_kernel(const int* __restrict__ colsum, int* __restrict__ bbase,
                                   int NB2, int E) {
    __shared__ int s[256];
    __shared__ int running;
    if (threadIdx.x == 0) running = 0;
    __syncthreads();
    for (int base = 0; base < NB2; base += 256) {
        int i = base + threadIdx.x;
        int v = (i < NB2) ? colsum[i] : 0;
        s[threadIdx.x] = v;
        __syncthreads();
        for (int off = 1; off < 256; off <<= 1) {
            int w = (threadIdx.x >= (unsigned)off) ? s[threadIdx.x - off] : 0;
            __syncthreads();
            s[threadIdx.x] += w;
            __syncthreads();
        }
        if (i < NB2) bbase[i] = running + s[threadIdx.x] - v;
        __syncthreads();
        if (threadIdx.x == 255) running += s[255];
        __syncthreads();
    }
    if (threadIdx.x == 0) bbase[NB2] = E;
}

__global__ void __launch_bounds__(1024) scatter_kernel(
                               const int* __restrict__ src, const int* __restrict__ dst,
                               const int* __restrict__ C, const int* __restrict__ bbase,
                               unsigned* __restrict__ bkt_data, int E, int CHUNK, int NB2) {
    extern __shared__ int ofs[];   // NB2 ints
    for (int i = threadIdx.x; i < NB2; i += 1024)
        ofs[i] = bbase[i] + C[(size_t)blockIdx.x * NB2 + i];
    __syncthreads();
    int s0 = blockIdx.x * CHUNK, s1 = min(s0 + CHUNK, E);
    for (int e = s0 + threadIdx.x; e < s1; e += 1024) {
        int d = dst[e];
        int p = atomicAdd(&ofs[d >> BSH], 1);   // LDS atomic only
        bkt_data[p] = ((unsigned)(d & (BSZ - 1)) << 17) | (unsigned)src[e];
    }
}

__global__ void __launch_bounds__(512) csr_build_kernel(
                                 const unsigned* __restrict__ bkt_data, const int* __restrict__ bbase,
                                 const float* __restrict__ x,
                                 unsigned* __restrict__ csr, int* __restrict__ e_start,
                                 float* __restrict__ dinv, float* __restrict__ xd,
                                 int N, int NB2) {
    __shared__ unsigned sdata[SCAP];
    __shared__ int hist[256];
    __shared__ int scn[256];
    __shared__ int bump[256];
    int tid = threadIdx.x;
    int b = blockIdx.x;
    int g0 = bbase[b], g1 = bbase[b + 1];
    int cnt = g1 - g0;
    bool fits = (cnt <= SCAP);
    if (tid < 256) hist[tid] = 0;
    __syncthreads();
    for (int i = tid; i < cnt; i += 512) {
        unsigned pk = bkt_data[g0 + i];
        if (fits) sdata[i] = pk;
        atomicAdd(&hist[pk >> 17], 1);
    }
    __syncthreads();
    int orig = (tid < 256) ? hist[tid] : 0;
    if (tid < 256) scn[tid] = orig;
    __syncthreads();
    for (int off = 1; off < 256; off <<= 1) {
        int w = (tid >= off && tid < 256) ? scn[tid - off] : 0;
        __syncthreads();
        if (tid < 256) scn[tid] += w;
        __syncthreads();
    }
    if (tid < 256) {
        int excl = scn[tid] - orig;
        bump[tid] = g0 + excl;
        int node = b * BSZ + tid;
        if (node < N) {
            float dv = rsqrtf((float)(orig + 1));
            dinv[node] = dv;
            xd[node] = x[node] * dv;
            e_start[node] = g0 + excl;
        }
    }
    if (b == NB2 - 1 && tid == 0) e_start[N] = g1;
    __syncthreads();
    for (int i = tid; i < cnt; i += 512) {
        unsigned pk = fits ? sdata[i] : bkt_data[g0 + i];
        int p = atomicAdd(&bump[pk >> 17], 1);
        csr[p] = pk & 0x1FFFFu;
    }
}

// ---------------- GCN layers: node-per-lane (CSR row per thread) ----------------
// Intermediate rows: bf16[32] = 64B/node (one cache line). No shuffles anywhere.

// agg1: s = sum xd[src] (scalar gather); u2[d][f] = dv * ((relu((dv*(s+xd_d))*W1+b1)) @ W2)
__global__ void __launch_bounds__(256) agg1_kernel(
                            const float* __restrict__ xd, const int* __restrict__ e_start,
                            const unsigned* __restrict__ csr, const float* __restrict__ dinv,
                            const float* __restrict__ W1, const float* __restrict__ b1,
                            const float* __restrict__ W2,
                            unsigned short* __restrict__ ub, int n) {
    __shared__ float sW2[1024];
    __shared__ float sW1[32], sb1[32];
    for (int i = threadIdx.x; i < 1024; i += 256) sW2[i] = W2[i];
    if (threadIdx.x < 32) { sW1[threadIdx.x] = W1[threadIdx.x]; sb1[threadIdx.x] = b1[threadIdx.x]; }
    __syncthreads();
    int d = blockIdx.x * 256 + threadIdx.x;
    if (d >= n) return;
    int e0 = e_start[d];
    int cnt = e_start[d + 1] - e0;
    float s = 0.f;
    int j = 0;
    for (; j + 4 <= cnt; j += 4) {
        int s0 = (int)csr[e0 + j], s1 = (int)csr[e0 + j + 1];
        int s2 = (int)csr[e0 + j + 2], s3 = (int)csr[e0 + j + 3];
        s += xd[s0]; s += xd[s1]; s += xd[s2]; s += xd[s3];
    }
    for (; j < cnt; j++) s += xd[(int)csr[e0 + j]];
    float dv = dinv[d];
    float tt = dv * (s + xd[d]);
    float h1[32];
#pragma unroll
    for (int f = 0; f < 32; f++) h1[f] = fmaxf(tt * sW1[f] + sb1[f], 0.f);
    float o[32];
#pragma unroll
    for (int f = 0; f < 32; f++) o[f] = 0.f;
#pragma unroll
    for (int k = 0; k < 32; k++) {
        float vk = h1[k];
#pragma unroll
        for (int fq = 0; fq < 8; fq++) {
            float4 w4 = *(const float4*)(sW2 + k * 32 + fq * 4);
            o[fq * 4 + 0] += vk * w4.x; o[fq * 4 + 1] += vk * w4.y;
            o[fq * 4 + 2] += vk * w4.z; o[fq * 4 + 3] += vk * w4.w;
        }
    }
    unsigned ow[16];
#pragma unroll
    for (int i2 = 0; i2 < 16; i2++) ow[i2] = bfpack(dv * o[2 * i2], dv * o[2 * i2 + 1]);
    uint4* dstp = (uint4*)(ub + ((size_t)d << 5));
    dstp[0] = *(uint4*)&ow[0];  dstp[1] = *(uint4*)&ow[4];
    dstp[2] = *(uint4*)&ow[8];  dstp[3] = *(uint4*)&ow[12];
}

// shared gather: acc[32] += sum of bf16 rows of all neighbors + self
__device__ __forceinline__ void row_gather(const unsigned short* __restrict__ ub,
                                           const unsigned* __restrict__ csr,
                                           int e0, int cnt, int d, float* acc) {
#pragma unroll
    for (int f = 0; f < 32; f++) acc[f] = 0.f;
    int j = 0;
    for (; j + 2 <= cnt; j += 2) {
        int s0 = (int)csr[e0 + j], s1 = (int)csr[e0 + j + 1];
        const uint4* r0 = (const uint4*)(ub + ((size_t)s0 << 5));
        const uint4* r1 = (const uint4*)(ub + ((size_t)s1 << 5));
        uint4 q0 = r0[0], q1 = r0[1], q2 = r0[2], q3 = r0[3];
        uint4 p0 = r1[0], p1 = r1[1], p2 = r1[2], p3 = r1[3];
        BF_ACC8(0, q0); BF_ACC8(8, q1); BF_ACC8(16, q2); BF_ACC8(24, q3);
        BF_ACC8(0, p0); BF_ACC8(8, p1); BF_ACC8(16, p2); BF_ACC8(24, p3);
    }
    if (j < cnt) {
        int s0 = (int)csr[e0 + j];
        const uint4* r0 = (const uint4*)(ub + ((size_t)s0 << 5));
        uint4 q0 = r0[0], q1 = r0[1], q2 = r0[2], q3 = r0[3];
        BF_ACC8(0, q0); BF_ACC8(8, q1); BF_ACC8(16, q2); BF_ACC8(24, q3);
    }
    const uint4* rs = (const uint4*)(ub + ((size_t)d << 5));   // self row
    uint4 q0 = rs[0], q1 = rs[1], q2 = rs[2], q3 = rs[3];
    BF_ACC8(0, q0); BF_ACC8(8, q1); BF_ACC8(16, q2); BF_ACC8(24, q3);
}

// agg2: ob[d] = bf16( dv * (relu(dv*acc + b) @ W) )
__global__ void __launch_bounds__(256, 2) agg2_kernel(
                            const unsigned short* __restrict__ ub,
                            const int* __restrict__ e_start, const unsigned* __restrict__ csr,
                            const float* __restrict__ dinv, const float* __restrict__ bias,
                            const float* __restrict__ W,
                            unsigned short* __restrict__ ob, int n) {
    __shared__ float sW[1024];
    __shared__ float sb[32];
    for (int i = threadIdx.x; i < 1024; i += 256) sW[i] = W[i];
    if (threadIdx.x < 32) sb[threadIdx.x] = bias[threadIdx.x];
    __syncthreads();
    int d = blockIdx.x * 256 + threadIdx.x;
    if (d >= n) return;
    int e0 = e_start[d];
    int cnt = e_start[d + 1] - e0;
    float acc[32];
    row_gather(ub, csr, e0, cnt, d, acc);
    float dv = dinv[d];
#pragma unroll
    for (int f = 0; f < 32; f++) acc[f] = fmaxf(dv * acc[f] + sb[f], 0.f);   // acc := v
    float o[32];
#pragma unroll
    for (int f = 0; f < 32; f++) o[f] = 0.f;
#pragma unroll
    for (int k = 0; k < 32; k++) {
        float vk = acc[k];
#pragma unroll
        for (int fq = 0; fq < 8; fq++) {
            float4 w4 = *(const float4*)(sW + k * 32 + fq * 4);
            o[fq * 4 + 0] += vk * w4.x; o[fq * 4 + 1] += vk * w4.y;
            o[fq * 4 + 2] += vk * w4.z; o[fq * 4 + 3] += vk * w4.w;
        }
    }
    unsigned ow[16];
#pragma unroll
    for (int i2 = 0; i2 < 16; i2++) ow[i2] = bfpack(dv * o[2 * i2], dv * o[2 * i2 + 1]);
    uint4* dstp = (uint4*)(ob + ((size_t)d << 5));
    dstp[0] = *(uint4*)&ow[0];  dstp[1] = *(uint4*)&ow[4];
    dstp[2] = *(uint4*)&ow[8];  dstp[3] = *(uint4*)&ow[12];
}

// agg3: v = relu(dv*acc + b3) -> hb (bf16) ; theta = PI*sigmoid(relu(v@Wt1+bt1)@Wt2 + bt2)
__global__ void __launch_bounds__(256, 2) agg3_kernel(
                            const unsigned short* __restrict__ ub,
                            const int* __restrict__ e_start, const unsigned* __restrict__ csr,
                            const float* __restrict__ dinv, const float* __restrict__ bias,
                            const float* __restrict__ Wt1, const float* __restrict__ bt1,
                            const float* __restrict__ Wt2, const float* __restrict__ bt2,
                            unsigned short* __restrict__ hb, float* __restrict__ theta, int n) {
    __shared__ float sW[1024];
    __shared__ float sb[32], sbt[32], sw2[32];
    for (int i = threadIdx.x; i < 1024; i += 256) sW[i] = Wt1[i];
    if (threadIdx.x < 32) {
        sb[threadIdx.x] = bias[threadIdx.x];
        sbt[threadIdx.x] = bt1[threadIdx.x];
        sw2[threadIdx.x] = Wt2[threadIdx.x];
    }
    __syncthreads();
    int d = blockIdx.x * 256 + threadIdx.x;
    if (d >= n) return;
    int e0 = e_start[d];
    int cnt = e_start[d + 1] - e0;
    float acc[32];
    row_gather(ub, csr, e0, cnt, d, acc);
    float dv = dinv[d];
#pragma unroll
    for (int f = 0; f < 32; f++) acc[f] = fmaxf(dv * acc[f] + sb[f], 0.f);   // acc := v = h row
    unsigned ow[16];
#pragma unroll
    for (int i2 = 0; i2 < 16; i2++) ow[i2] = bfpack(acc[2 * i2], acc[2 * i2 + 1]);
    uint4* dstp = (uint4*)(hb + ((size_t)d << 5));
    dstp[0] = *(uint4*)&ow[0];  dstp[1] = *(uint4*)&ow[4];
    dstp[2] = *(uint4*)&ow[8];  dstp[3] = *(uint4*)&ow[12];
    float o[32];
#pragma unroll
    for (int f = 0; f < 32; f++) o[f] = 0.f;
#pragma unroll
    for (int k = 0; k < 32; k++) {
        float vk = acc[k];
#pragma unroll
        for (int fq = 0; fq < 8; fq++) {
            float4 w4 = *(const float4*)(sW + k * 32 + fq * 4);
            o[fq * 4 + 0] += vk * w4.x; o[fq * 4 + 1] += vk * w4.y;
            o[fq * 4 + 2] += vk * w4.z; o[fq * 4 + 3] += vk * w4.w;
        }
    }
    float tl = 0.f;
#pragma unroll
    for (int f = 0; f < 32; f++) tl += fmaxf(o[f] + sbt[f], 0.f) * sw2[f];
    theta[d] = PI_F / (1.f + __expf(-(tl + bt2[0])));
}

// ---------------- pooled head: boundary index + block-per-graph reduce ----------------

__global__ void gb_kernel(const int* __restrict__ batch, int* __restrict__ gstart,
                          int n, int G) {
    int i = blockIdx.x * 256 + threadIdx.x;
    if (i >= n) return;
    int g = batch[i];
    if (i == 0) {
        for (int gg = 0; gg <= g; gg++) gstart[gg] = 0;
    } else {
        int gp = batch[i - 1];
        for (int gg = gp + 1; gg <= g; gg++) gstart[gg] = i;
    }
    if (i == n - 1) {
        for (int gg = g + 1; gg <= G; gg++) gstart[gg] = n;
    }
}

__global__ void __launch_bounds__(512) bg_kernel(
                          const unsigned short* __restrict__ hb, const int* __restrict__ gstart,
                          const float* __restrict__ Wg1, const float* __restrict__ bg1v,
                          const float* __restrict__ Wg2, const float* __restrict__ bg2v,
                          float* __restrict__ out, int G) {
    __shared__ float sW[1024];
    __shared__ float part[8][32];
    for (int i = threadIdx.x; i < 1024; i += 512) sW[i] = Wg1[i];
    int g = blockIdx.x;
    int s = gstart[g], e = gstart[g + 1];
    int w = threadIdx.x >> 6;
    int lane = threadIdx.x & 63;
    int f = lane & 31, h = lane >> 5;
    float a = 0.f;
    for (int i = s + (w << 1) + h; i < e; i += 16)
        a += __uint_as_float((unsigned)hb[((size_t)i << 5) + f] << 16);
    a += __shfl_xor(a, 32, 64);
    if (h == 0) part[w][f] = a;
    __syncthreads();
    if (w == 0) {
        float hv = 0.f;
#pragma unroll
        for (int p = 0; p < 8; p++) hv += part[p][f];
        hv /= fmaxf((float)(e - s), 1.f);
        int base = lane & 32;
        float acc = bg1v[f];
#pragma unroll
        for (int k = 0; k < 32; k++) acc += __shfl(hv, base | k, 64) * sW[k * 32 + f];
        acc = fmaxf(acc, 0.f);
        float p0 = acc * Wg2[f * 2 + 0];
        float p1 = acc * Wg2[f * 2 + 1];
#pragma unroll
        for (int m = 1; m < 32; m <<= 1) {
            p0 += __shfl_xor(p0, m, 64);
            p1 += __shfl_xor(p1, m, 64);
        }
        if (lane == 0) {
            out[g * 2 + 0] = 2.f * PI_F / (1.f + __expf(-(p0 + bg2v[0])));
            out[g * 2 + 1] = 2.f * PI_F / (1.f + __expf(-(p1 + bg2v[1])));
        }
    }
}

// ---------------- launch ----------------

extern "C" void kernel_launch(void* const* d_in, const int* in_sizes, int n_in,
                              void* d_out, int out_size, void* d_ws, size_t ws_size,
                              hipStream_t stream) {
    const float* x   = (const float*)d_in[0];
    const int*   ei  = (const int*)d_in[1];
    const int* batch = (const int*)d_in[2];
    const float* W1  = (const float*)d_in[3];
    const float* b1  = (const float*)d_in[4];
    const float* W2  = (const float*)d_in[5];
    const float* b2  = (const float*)d_in[6];
    const float* W3  = (const float*)d_in[7];
    const float* b3  = (const float*)d_in[8];
    const float* Wt1 = (const float*)d_in[9];
    const float* bt1 = (const float*)d_in[10];
    const float* Wt2 = (const float*)d_in[11];
    const float* bt2 = (const float*)d_in[12];
    const float* Wg1 = (const float*)d_in[13];
    const float* bg1 = (const float*)d_in[14];
    const float* Wg2 = (const float*)d_in[15];
    const float* bg2 = (const float*)d_in[16];

    const int N = in_sizes[0];
    const int E = in_sizes[1] / 2;
    const int G = 128;
    const int* src = ei;
    const int* dst = ei + E;
    float* theta_out = (float*)d_out;
    float* bg_out = (float*)d_out + N;

    const int NB2 = (N + BSZ - 1) >> BSH;
    const int CHUNK = (E + NBLK - 1) / NBLK;

    char* w = (char*)d_ws;
    auto alloc = [&](size_t bytes) -> char* { char* p = w; w += align256(bytes); return p; };
    int*      C        = (int*)alloc((size_t)NBLK * NB2 * 4);
    int*      colsum   = (int*)alloc((size_t)NB2 * 4);
    int*      bbase    = (int*)alloc((size_t)(NB2 + 1) * 4);
    unsigned* bkt_data = (unsigned*)alloc((size_t)E * 4);
    unsigned* csr      = (unsigned*)alloc((size_t)E * 4);
    int*      e_start  = (int*)alloc((size_t)(N + 1) * 4);
    float*    dinv     = (float*)alloc((size_t)N * 4);
    float*    xd       = (float*)alloc((size_t)N * 4);
    unsigned short* u2b = (unsigned short*)alloc((size_t)N * 64);
    unsigned short* u3b = (unsigned short*)alloc((size_t)N * 64);
    unsigned short* hb  = (unsigned short*)alloc((size_t)N * 64);
    int*      gstart   = (int*)alloc((size_t)(G + 1) * 4);

    size_t ldsB = (size_t)NB2 * 4;
    count_kernel<<<NBLK, 1024, ldsB, stream>>>(dst, C, E, CHUNK, NB2);
    scan_blocks_kernel<<<NB2, 256, 0, stream>>>(C, colsum, NB2);
    scan_totals_kernel<<<1, 256, 0, stream>>>(colsum, bbase, NB2, E);
    scatter_kernel<<<NBLK, 1024, ldsB, stream>>>(src, dst, C, bbase, bkt_data, E, CHUNK, NB2);
    csr_build_kernel<<<NB2, 512, 0, stream>>>(bkt_data, bbase, x, csr, e_start, dinv, xd, N, NB2);
    gb_kernel<<<(N + 255) / 256, 256, 0, stream>>>(batch, gstart, N, G);

    unsigned gridN = (unsigned)((N + 255) / 256);   // node-per-lane: 256 nodes per block

    agg1_kernel<<<gridN, 256, 0, stream>>>(xd, e_start, csr, dinv, W1, b1, W2, u2b, N);
    agg2_kernel<<<gridN, 256, 0, stream>>>(u2b, e_start, csr, dinv, b2, W3, u3b, N);
    agg3_kernel<<<gridN, 256, 0, stream>>>(u3b, e_start, csr, dinv, b3,
                                           Wt1, bt1, Wt2, bt2, hb, theta_out, N);

    bg_kernel<<<G, 512, 0, stream>>>(hb, gstart, Wg1, bg1, Wg2, bg2, bg_out, G);
}

// Round 6
// 294.583 us; speedup vs baseline: 2.7828x; 1.1392x over previous
//
#include <hip/hip_runtime.h>
#include <hip/hip_bf16.h>

#define PI_F 3.14159265358979323846f
#define NBLK 256     // chunk count for count/scatter passes (scan width)
#define BSH 8        // coarse bucket = 256 dst nodes
#define BSZ 256      // nodes per bucket
#define SCAP 10240   // LDS edge staging capacity (mean 8192, +22 sigma)

static inline size_t align256(size_t x) { return (x + 255) & ~size_t(255); }

// bf16 helpers (bit tricks; round-to-nearest via +0x8000)
__device__ __forceinline__ float bflo(unsigned w) { return __uint_as_float(w << 16); }
__device__ __forceinline__ float bfhi(unsigned w) { return __uint_as_float(w & 0xFFFF0000u); }
__device__ __forceinline__ unsigned bfpack(float a, float b) {
    unsigned lo = (__float_as_uint(a) + 0x8000u) >> 16;
    unsigned hi = (__float_as_uint(b) + 0x8000u) & 0xFFFF0000u;
    return lo | hi;
}

// accumulate one 16B row-quarter (8 bf16 features) into acc[8]
#define BF_ACC8Q(q) \
    acc[0] += bflo((q).x); acc[1] += bfhi((q).x); \
    acc[2] += bflo((q).y); acc[3] += bfhi((q).y); \
    acc[4] += bflo((q).z); acc[5] += bfhi((q).z); \
    acc[6] += bflo((q).w); acc[7] += bfhi((q).w);

// ---------------- atomic-free bucketed CSR build ----------------

__global__ void __launch_bounds__(1024) count_kernel(
                             const int* __restrict__ dst, int* __restrict__ C,
                             int E, int CHUNK, int NB2) {
    extern __shared__ int hist[];   // NB2 ints
    for (int i = threadIdx.x; i < NB2; i += 1024) hist[i] = 0;
    __syncthreads();
    int s0 = blockIdx.x * CHUNK, s1 = min(s0 + CHUNK, E);
    for (int e = s0 + threadIdx.x; e < s1; e += 1024)
        atomicAdd(&hist[dst[e] >> BSH], 1);
    __syncthreads();
    for (int i = threadIdx.x; i < NB2; i += 1024)
        C[(size_t)blockIdx.x * NB2 + i] = hist[i];
}

__global__ void scan_blocks_kernel(int* __restrict__ C, int* __restrict__ colsum, int NB2) {
    __shared__ int s[256];
    int k = blockIdx.x;
    int b = threadIdx.x;
    int v = C[(size_t)b * NB2 + k];
    s[b] = v;
    __syncthreads();
    for (int off = 1; off < 256; off <<= 1) {
        int w = (b >= off) ? s[b - off] : 0;
        __syncthreads();
        s[b] += w;
        __syncthreads();
    }
    C[(size_t)b * NB2 + k] = s[b] - v;   // exclusive
    if (b == 255) colsum[k] = s[255];
}

__global__ void scan_totals_kernel(const int* __restrict__ colsum, int* __restrict__ bbase,
                                   int NB2, int E) {
    __shared__ int s[256];
    __shared__ int running;
    if (threadIdx.x == 0) running = 0;
    __syncthreads();
    for (int base = 0; base < NB2; base += 256) {
        int i = base + threadIdx.x;
        int v = (i < NB2) ? colsum[i] : 0;
        s[threadIdx.x] = v;
        __syncthreads();
        for (int off = 1; off < 256; off <<= 1) {
            int w = (threadIdx.x >= (unsigned)off) ? s[threadIdx.x - off] : 0;
            __syncthreads();
            s[threadIdx.x] += w;
            __syncthreads();
        }
        if (i < NB2) bbase[i] = running + s[threadIdx.x] - v;
        __syncthreads();
        if (threadIdx.x == 255) running += s[255];
        __syncthreads();
    }
    if (threadIdx.x == 0) bbase[NB2] = E;
}

__global__ void __launch_bounds__(1024) scatter_kernel(
                               const int* __restrict__ src, const int* __restrict__ dst,
                               const int* __restrict__ C, const int* __restrict__ bbase,
                               unsigned* __restrict__ bkt_data, int E, int CHUNK, int NB2) {
    extern __shared__ int ofs[];   // NB2 ints
    for (int i = threadIdx.x; i < NB2; i += 1024)
        ofs[i] = bbase[i] + C[(size_t)blockIdx.x * NB2 + i];
    __syncthreads();
    int s0 = blockIdx.x * CHUNK, s1 = min(s0 + CHUNK, E);
    for (int e = s0 + threadIdx.x; e < s1; e += 1024) {
        int d = dst[e];
        int p = atomicAdd(&ofs[d >> BSH], 1);   // LDS atomic only
        bkt_data[p] = ((unsigned)(d & (BSZ - 1)) << 17) | (unsigned)src[e];
    }
}

__global__ void __launch_bounds__(512) csr_build_kernel(
                                 const unsigned* __restrict__ bkt_data, const int* __restrict__ bbase,
                                 const float* __restrict__ x,
                                 unsigned* __restrict__ csr, int* __restrict__ e_start,
                                 float* __restrict__ dinv, float* __restrict__ xd,
                                 int N, int NB2) {
    __shared__ unsigned sdata[SCAP];
    __shared__ int hist[256];
    __shared__ int scn[256];
    __shared__ int bump[256];
    int tid = threadIdx.x;
    int b = blockIdx.x;
    int g0 = bbase[b], g1 = bbase[b + 1];
    int cnt = g1 - g0;
    bool fits = (cnt <= SCAP);
    if (tid < 256) hist[tid] = 0;
    __syncthreads();
    for (int i = tid; i < cnt; i += 512) {
        unsigned pk = bkt_data[g0 + i];
        if (fits) sdata[i] = pk;
        atomicAdd(&hist[pk >> 17], 1);
    }
    __syncthreads();
    int orig = (tid < 256) ? hist[tid] : 0;
    if (tid < 256) scn[tid] = orig;
    __syncthreads();
    for (int off = 1; off < 256; off <<= 1) {
        int w = (tid >= off && tid < 256) ? scn[tid - off] : 0;
        __syncthreads();
        if (tid < 256) scn[tid] += w;
        __syncthreads();
    }
    if (tid < 256) {
        int excl = scn[tid] - orig;
        bump[tid] = g0 + excl;
        int node = b * BSZ + tid;
        if (node < N) {
            float dv = rsqrtf((float)(orig + 1));
            dinv[node] = dv;
            xd[node] = x[node] * dv;
            e_start[node] = g0 + excl;
        }
    }
    if (b == NB2 - 1 && tid == 0) e_start[N] = g1;
    __syncthreads();
    for (int i = tid; i < cnt; i += 512) {
        unsigned pk = fits ? sdata[i] : bkt_data[g0 + i];
        int p = atomicAdd(&bump[pk >> 17], 1);
        csr[p] = pk & 0x1FFFFu;
    }
}

// ---------------- GCN layers: 4 threads per node (feature-quarter each) ----------------
// Intermediate rows: bf16[32] = 64B/node. sub = tid&3 owns features [sub*8, sub*8+8).
// Gather needs no shuffles (disjoint features); matmul exchanges v via 32 quad-shuffles.

// o[0..7] += full 32-k matvec: o[f] = sum_k v[k] * W[k][sub*8+f], W row-major in LDS.
__device__ __forceinline__ void mm32_8(const float* __restrict__ sW, const float vr[8],
                                       int sub, int lane, float o[8]) {
    const float4* sW4 = (const float4*)sW;
    int base = lane & ~3;
#pragma unroll
    for (int r = 0; r < 4; r++) {
#pragma unroll
        for (int i = 0; i < 8; i++) {
            float vk = __shfl(vr[i], base | r, 64);
            int k = r * 8 + i;
            float4 w0 = sW4[k * 8 + sub * 2];
            float4 w1 = sW4[k * 8 + sub * 2 + 1];
            o[0] += vk * w0.x; o[1] += vk * w0.y; o[2] += vk * w0.z; o[3] += vk * w0.w;
            o[4] += vk * w1.x; o[5] += vk * w1.y; o[6] += vk * w1.z; o[7] += vk * w1.w;
        }
    }
}

// agg1: rank-1 gather (scalar xd), strided over 4 subs + quad-reduce; then fused MLP.
__global__ void __launch_bounds__(256) agg1_kernel(
                            const float* __restrict__ xd, const int* __restrict__ e_start,
                            const unsigned* __restrict__ csr, const float* __restrict__ dinv,
                            const float* __restrict__ W1, const float* __restrict__ b1,
                            const float* __restrict__ W2,
                            unsigned short* __restrict__ ub, int n) {
    __shared__ float sW2[1024];
    __shared__ float sW1[32], sb1[32];
    for (int i = threadIdx.x; i < 1024; i += 256) sW2[i] = W2[i];
    if (threadIdx.x < 32) { sW1[threadIdx.x] = W1[threadIdx.x]; sb1[threadIdx.x] = b1[threadIdx.x]; }
    __syncthreads();
    int t = blockIdx.x * 256 + threadIdx.x;
    int d = t >> 2, sub = t & 3;
    int lane = threadIdx.x & 63;
    if (d >= n) return;
    int e0 = e_start[d];
    int cnt = e_start[d + 1] - e0;
    float s = 0.f;
    int j = sub;
    for (; j + 8 <= cnt; j += 8) {
        int i0 = (int)csr[e0 + j], i1 = (int)csr[e0 + j + 4];
        s += xd[i0]; s += xd[i1];
    }
    for (; j < cnt; j += 4) s += xd[(int)csr[e0 + j]];
    s += __shfl_xor(s, 1, 64);
    s += __shfl_xor(s, 2, 64);
    float dv = dinv[d];
    float tt = dv * (s + xd[d]);
    float vr[8];
#pragma unroll
    for (int i = 0; i < 8; i++) vr[i] = fmaxf(tt * sW1[sub * 8 + i] + sb1[sub * 8 + i], 0.f);
    float o[8];
#pragma unroll
    for (int i = 0; i < 8; i++) o[i] = 0.f;
    mm32_8(sW2, vr, sub, lane, o);
    unsigned ow[4];
#pragma unroll
    for (int i2 = 0; i2 < 4; i2++) ow[i2] = bfpack(dv * o[2 * i2], dv * o[2 * i2 + 1]);
    ((uint4*)ub)[(size_t)d * 4 + sub] = *(uint4*)&ow[0];
}

// agg2: gather quarter-rows of all neighbors + self; v=relu(dv*acc+b); out=bf16(dv*(v@W)).
__global__ void __launch_bounds__(256) agg2_kernel(
                            const unsigned short* __restrict__ ub,
                            const int* __restrict__ e_start, const unsigned* __restrict__ csr,
                            const float* __restrict__ dinv, const float* __restrict__ bias,
                            const float* __restrict__ W,
                            unsigned short* __restrict__ ob, int n) {
    __shared__ float sW[1024];
    __shared__ float sb[32];
    for (int i = threadIdx.x; i < 1024; i += 256) sW[i] = W[i];
    if (threadIdx.x < 32) sb[threadIdx.x] = bias[threadIdx.x];
    __syncthreads();
    int t = blockIdx.x * 256 + threadIdx.x;
    int d = t >> 2, sub = t & 3;
    int lane = threadIdx.x & 63;
    if (d >= n) return;
    int e0 = e_start[d];
    int cnt = e_start[d + 1] - e0;
    float acc[8];
#pragma unroll
    for (int i = 0; i < 8; i++) acc[i] = 0.f;
    const uint4* rows = (const uint4*)ub;
    int j = 0;
    for (; j + 4 <= cnt; j += 4) {
        int i0 = (int)csr[e0 + j],     i1 = (int)csr[e0 + j + 1];
        int i2 = (int)csr[e0 + j + 2], i3 = (int)csr[e0 + j + 3];
        uint4 q0 = rows[(size_t)i0 * 4 + sub];
        uint4 q1 = rows[(size_t)i1 * 4 + sub];
        uint4 q2 = rows[(size_t)i2 * 4 + sub];
        uint4 q3 = rows[(size_t)i3 * 4 + sub];
        BF_ACC8Q(q0); BF_ACC8Q(q1); BF_ACC8Q(q2); BF_ACC8Q(q3);
    }
    for (; j < cnt; j++) {
        int i0 = (int)csr[e0 + j];
        uint4 q0 = rows[(size_t)i0 * 4 + sub];
        BF_ACC8Q(q0);
    }
    {   // self row
        uint4 q0 = rows[(size_t)d * 4 + sub];
        BF_ACC8Q(q0);
    }
    float dv = dinv[d];
    float vr[8];
#pragma unroll
    for (int i = 0; i < 8; i++) vr[i] = fmaxf(dv * acc[i] + sb[sub * 8 + i], 0.f);
    float o[8];
#pragma unroll
    for (int i = 0; i < 8; i++) o[i] = 0.f;
    mm32_8(sW, vr, sub, lane, o);
    unsigned ow[4];
#pragma unroll
    for (int i2 = 0; i2 < 4; i2++) ow[i2] = bfpack(dv * o[2 * i2], dv * o[2 * i2 + 1]);
    ((uint4*)ob)[(size_t)d * 4 + sub] = *(uint4*)&ow[0];
}

// agg3: v=relu(dv*acc+b3) -> hb (bf16 quarter); theta = PI*sigmoid(relu(v@Wt1+bt1)@Wt2+bt2).
__global__ void __launch_bounds__(256) agg3_kernel(
                            const unsigned short* __restrict__ ub,
                            const int* __restrict__ e_start, const unsigned* __restrict__ csr,
                            const float* __restrict__ dinv, const float* __restrict__ bias,
                            const float* __restrict__ Wt1, const float* __restrict__ bt1,
                            const float* __restrict__ Wt2, const float* __restrict__ bt2,
                            unsigned short* __restrict__ hb, float* __restrict__ theta, int n) {
    __shared__ float sW[1024];
    __shared__ float sb[32], sbt[32], sw2[32];
    for (int i = threadIdx.x; i < 1024; i += 256) sW[i] = Wt1[i];
    if (threadIdx.x < 32) {
        sb[threadIdx.x] = bias[threadIdx.x];
        sbt[threadIdx.x] = bt1[threadIdx.x];
        sw2[threadIdx.x] = Wt2[threadIdx.x];
    }
    __syncthreads();
    int t = blockIdx.x * 256 + threadIdx.x;
    int d = t >> 2, sub = t & 3;
    int lane = threadIdx.x & 63;
    if (d >= n) return;
    int e0 = e_start[d];
    int cnt = e_start[d + 1] - e0;
    float acc[8];
#pragma unroll
    for (int i = 0; i < 8; i++) acc[i] = 0.f;
    const uint4* rows = (const uint4*)ub;
    int j = 0;
    for (; j + 4 <= cnt; j += 4) {
        int i0 = (int)csr[e0 + j],     i1 = (int)csr[e0 + j + 1];
        int i2 = (int)csr[e0 + j + 2], i3 = (int)csr[e0 + j + 3];
        uint4 q0 = rows[(size_t)i0 * 4 + sub];
        uint4 q1 = rows[(size_t)i1 * 4 + sub];
        uint4 q2 = rows[(size_t)i2 * 4 + sub];
        uint4 q3 = rows[(size_t)i3 * 4 + sub];
        BF_ACC8Q(q0); BF_ACC8Q(q1); BF_ACC8Q(q2); BF_ACC8Q(q3);
    }
    for (; j < cnt; j++) {
        int i0 = (int)csr[e0 + j];
        uint4 q0 = rows[(size_t)i0 * 4 + sub];
        BF_ACC8Q(q0);
    }
    {   // self row
        uint4 q0 = rows[(size_t)d * 4 + sub];
        BF_ACC8Q(q0);
    }
    float dv = dinv[d];
    float vr[8];
#pragma unroll
    for (int i = 0; i < 8; i++) vr[i] = fmaxf(dv * acc[i] + sb[sub * 8 + i], 0.f);
    unsigned ow[4];
#pragma unroll
    for (int i2 = 0; i2 < 4; i2++) ow[i2] = bfpack(vr[2 * i2], vr[2 * i2 + 1]);
    ((uint4*)hb)[(size_t)d * 4 + sub] = *(uint4*)&ow[0];
    float o[8];
#pragma unroll
    for (int i = 0; i < 8; i++) o[i] = 0.f;
    mm32_8(sW, vr, sub, lane, o);
    float tl = 0.f;
#pragma unroll
    for (int i = 0; i < 8; i++)
        tl += fmaxf(o[i] + sbt[sub * 8 + i], 0.f) * sw2[sub * 8 + i];
    tl += __shfl_xor(tl, 1, 64);
    tl += __shfl_xor(tl, 2, 64);
    if (sub == 0) theta[d] = PI_F / (1.f + __expf(-(tl + bt2[0])));
}

// ---------------- pooled head: boundary index + block-per-graph reduce ----------------

__global__ void gb_kernel(const int* __restrict__ batch, int* __restrict__ gstart,
                          int n, int G) {
    int i = blockIdx.x * 256 + threadIdx.x;
    if (i >= n) return;
    int g = batch[i];
    if (i == 0) {
        for (int gg = 0; gg <= g; gg++) gstart[gg] = 0;
    } else {
        int gp = batch[i - 1];
        for (int gg = gp + 1; gg <= g; gg++) gstart[gg] = i;
    }
    if (i == n - 1) {
        for (int gg = g + 1; gg <= G; gg++) gstart[gg] = n;
    }
}

__global__ void __launch_bounds__(512) bg_kernel(
                          const unsigned short* __restrict__ hb, const int* __restrict__ gstart,
                          const float* __restrict__ Wg1, const float* __restrict__ bg1v,
                          const float* __restrict__ Wg2, const float* __restrict__ bg2v,
                          float* __restrict__ out, int G) {
    __shared__ float sW[1024];
    __shared__ float part[8][32];
    for (int i = threadIdx.x; i < 1024; i += 512) sW[i] = Wg1[i];
    int g = blockIdx.x;
    int s = gstart[g], e = gstart[g + 1];
    int w = threadIdx.x >> 6;
    int lane = threadIdx.x & 63;
    int f = lane & 31, h = lane >> 5;
    float a = 0.f;
    for (int i = s + (w << 1) + h; i < e; i += 16)
        a += __uint_as_float((unsigned)hb[((size_t)i << 5) + f] << 16);
    a += __shfl_xor(a, 32, 64);
    if (h == 0) part[w][f] = a;
    __syncthreads();
    if (w == 0) {
        float hv = 0.f;
#pragma unroll
        for (int p = 0; p < 8; p++) hv += part[p][f];
        hv /= fmaxf((float)(e - s), 1.f);
        int base = lane & 32;
        float acc = bg1v[f];
#pragma unroll
        for (int k = 0; k < 32; k++) acc += __shfl(hv, base | k, 64) * sW[k * 32 + f];
        acc = fmaxf(acc, 0.f);
        float p0 = acc * Wg2[f * 2 + 0];
        float p1 = acc * Wg2[f * 2 + 1];
#pragma unroll
        for (int m = 1; m < 32; m <<= 1) {
            p0 += __shfl_xor(p0, m, 64);
            p1 += __shfl_xor(p1, m, 64);
        }
        if (lane == 0) {
            out[g * 2 + 0] = 2.f * PI_F / (1.f + __expf(-(p0 + bg2v[0])));
            out[g * 2 + 1] = 2.f * PI_F / (1.f + __expf(-(p1 + bg2v[1])));
        }
    }
}

// ---------------- launch ----------------

extern "C" void kernel_launch(void* const* d_in, const int* in_sizes, int n_in,
                              void* d_out, int out_size, void* d_ws, size_t ws_size,
                              hipStream_t stream) {
    const float* x   = (const float*)d_in[0];
    const int*   ei  = (const int*)d_in[1];
    const int* batch = (const int*)d_in[2];
    const float* W1  = (const float*)d_in[3];
    const float* b1  = (const float*)d_in[4];
    const float* W2  = (const float*)d_in[5];
    const float* b2  = (const float*)d_in[6];
    const float* W3  = (const float*)d_in[7];
    const float* b3  = (const float*)d_in[8];
    const float* Wt1 = (const float*)d_in[9];
    const float* bt1 = (const float*)d_in[10];
    const float* Wt2 = (const float*)d_in[11];
    const float* bt2 = (const float*)d_in[12];
    const float* Wg1 = (const float*)d_in[13];
    const float* bg1 = (const float*)d_in[14];
    const float* Wg2 = (const float*)d_in[15];
    const float* bg2 = (const float*)d_in[16];

    const int N = in_sizes[0];
    const int E = in_sizes[1] / 2;
    const int G = 128;
    const int* src = ei;
    const int* dst = ei + E;
    float* theta_out = (float*)d_out;
    float* bg_out = (float*)d_out + N;

    const int NB2 = (N + BSZ - 1) >> BSH;
    const int CHUNK = (E + NBLK - 1) / NBLK;

    char* w = (char*)d_ws;
    auto alloc = [&](size_t bytes) -> char* { char* p = w; w += align256(bytes); return p; };
    int*      C        = (int*)alloc((size_t)NBLK * NB2 * 4);
    int*      colsum   = (int*)alloc((size_t)NB2 * 4);
    int*      bbase    = (int*)alloc((size_t)(NB2 + 1) * 4);
    unsigned* bkt_data = (unsigned*)alloc((size_t)E * 4);
    unsigned* csr      = (unsigned*)alloc((size_t)E * 4);
    int*      e_start  = (int*)alloc((size_t)(N + 1) * 4);
    float*    dinv     = (float*)alloc((size_t)N * 4);
    float*    xd       = (float*)alloc((size_t)N * 4);
    unsigned short* u2b = (unsigned short*)alloc((size_t)N * 64);
    unsigned short* u3b = (unsigned short*)alloc((size_t)N * 64);
    unsigned short* hb  = (unsigned short*)alloc((size_t)N * 64);
    int*      gstart   = (int*)alloc((size_t)(G + 1) * 4);

    size_t ldsB = (size_t)NB2 * 4;
    count_kernel<<<NBLK, 1024, ldsB, stream>>>(dst, C, E, CHUNK, NB2);
    scan_blocks_kernel<<<NB2, 256, 0, stream>>>(C, colsum, NB2);
    scan_totals_kernel<<<1, 256, 0, stream>>>(colsum, bbase, NB2, E);
    scatter_kernel<<<NBLK, 1024, ldsB, stream>>>(src, dst, C, bbase, bkt_data, E, CHUNK, NB2);
    csr_build_kernel<<<NB2, 512, 0, stream>>>(bkt_data, bbase, x, csr, e_start, dinv, xd, N, NB2);
    gb_kernel<<<(N + 255) / 256, 256, 0, stream>>>(batch, gstart, N, G);

    unsigned gridQ = (unsigned)(((size_t)N * 4 + 255) / 256);   // 4 threads per node

    agg1_kernel<<<gridQ, 256, 0, stream>>>(xd, e_start, csr, dinv, W1, b1, W2, u2b, N);
    agg2_kernel<<<gridQ, 256, 0, stream>>>(u2b, e_start, csr, dinv, b2, W3, u3b, N);
    agg3_kernel<<<gridQ, 256, 0, stream>>>(u3b, e_start, csr, dinv, b3,
                                           Wt1, bt1, Wt2, bt2, hb, theta_out, N);

    bg_kernel<<<G, 512, 0, stream>>>(hb, gstart, Wg1, bg1, Wg2, bg2, bg_out, G);
}

// Round 7
// 287.834 us; speedup vs baseline: 2.8481x; 1.0234x over previous
//
#include <hip/hip_runtime.h>
#include <hip/hip_bf16.h>

#define PI_F 3.14159265358979323846f
#define NBLK 256     // chunk count for count/scatter passes (scan width)
#define BSH 8        // coarse bucket = 256 dst nodes
#define BSZ 256      // nodes per bucket
#define SCAP 10240   // LDS edge staging capacity (mean 8192, +22 sigma)

static inline size_t align256(size_t x) { return (x + 255) & ~size_t(255); }

typedef float v2f __attribute__((ext_vector_type(2)));

// bf16 helpers (bit tricks; round-to-nearest via +0x8000)
__device__ __forceinline__ unsigned bfpack(float a, float b) {
    unsigned lo = (__float_as_uint(a) + 0x8000u) >> 16;
    unsigned hi = (__float_as_uint(b) + 0x8000u) & 0xFFFF0000u;
    return lo | hi;
}

// accumulate one 8B fp8 row-quarter (8 features) scaled by rs into acc[8]
__device__ __forceinline__ void f8acc(uint2 q, float rs, float acc[8]) {
    v2f l0 = __builtin_amdgcn_cvt_pk_f32_fp8(q.x, false);
    v2f h0 = __builtin_amdgcn_cvt_pk_f32_fp8(q.x, true);
    v2f l1 = __builtin_amdgcn_cvt_pk_f32_fp8(q.y, false);
    v2f h1 = __builtin_amdgcn_cvt_pk_f32_fp8(q.y, true);
    acc[0] += rs * l0.x; acc[1] += rs * l0.y; acc[2] += rs * h0.x; acc[3] += rs * h0.y;
    acc[4] += rs * l1.x; acc[5] += rs * l1.y; acc[6] += rs * h1.x; acc[7] += rs * h1.y;
}

// ---------------- atomic-free bucketed CSR build ----------------

__global__ void __launch_bounds__(1024) count_kernel(
                             const int* __restrict__ dst, int* __restrict__ C,
                             int E, int CHUNK, int NB2) {
    extern __shared__ int hist[];   // NB2 ints
    for (int i = threadIdx.x; i < NB2; i += 1024) hist[i] = 0;
    __syncthreads();
    int s0 = blockIdx.x * CHUNK, s1 = min(s0 + CHUNK, E);
    for (int e = s0 + threadIdx.x; e < s1; e += 1024)
        atomicAdd(&hist[dst[e] >> BSH], 1);
    __syncthreads();
    for (int i = threadIdx.x; i < NB2; i += 1024)
        C[(size_t)blockIdx.x * NB2 + i] = hist[i];
}

__global__ void scan_blocks_kernel(int* __restrict__ C, int* __restrict__ colsum, int NB2) {
    __shared__ int s[256];
    int k = blockIdx.x;
    int b = threadIdx.x;
    int v = C[(size_t)b * NB2 + k];
    s[b] = v;
    __syncthreads();
    for (int off = 1; off < 256; off <<= 1) {
        int w = (b >= off) ? s[b - off] : 0;
        __syncthreads();
        s[b] += w;
        __syncthreads();
    }
    C[(size_t)b * NB2 + k] = s[b] - v;   // exclusive
    if (b == 255) colsum[k] = s[255];
}

__global__ void scan_totals_kernel(const int* __restrict__ colsum, int* __restrict__ bbase,
                                   int NB2, int E) {
    __shared__ int s[256];
    __shared__ int running;
    if (threadIdx.x == 0) running = 0;
    __syncthreads();
    for (int base = 0; base < NB2; base += 256) {
        int i = base + threadIdx.x;
        int v = (i < NB2) ? colsum[i] : 0;
        s[threadIdx.x] = v;
        __syncthreads();
        for (int off = 1; off < 256; off <<= 1) {
            int w = (threadIdx.x >= (unsigned)off) ? s[threadIdx.x - off] : 0;
            __syncthreads();
            s[threadIdx.x] += w;
            __syncthreads();
        }
        if (i < NB2) bbase[i] = running + s[threadIdx.x] - v;
        __syncthreads();
        if (threadIdx.x == 255) running += s[255];
        __syncthreads();
    }
    if (threadIdx.x == 0) bbase[NB2] = E;
}

__global__ void __launch_bounds__(1024) scatter_kernel(
                               const int* __restrict__ src, const int* __restrict__ dst,
                               const int* __restrict__ C, const int* __restrict__ bbase,
                               unsigned* __restrict__ bkt_data, int E, int CHUNK, int NB2) {
    extern __shared__ int ofs[];   // NB2 ints
    for (int i = threadIdx.x; i < NB2; i += 1024)
        ofs[i] = bbase[i] + C[(size_t)blockIdx.x * NB2 + i];
    __syncthreads();
    int s0 = blockIdx.x * CHUNK, s1 = min(s0 + CHUNK, E);
    for (int e = s0 + threadIdx.x; e < s1; e += 1024) {
        int d = dst[e];
        int p = atomicAdd(&ofs[d >> BSH], 1);   // LDS atomic only
        bkt_data[p] = ((unsigned)(d & (BSZ - 1)) << 17) | (unsigned)src[e];
    }
}

__global__ void __launch_bounds__(512) csr_build_kernel(
                                 const unsigned* __restrict__ bkt_data, const int* __restrict__ bbase,
                                 const float* __restrict__ x,
                                 unsigned* __restrict__ csr, int* __restrict__ e_start,
                                 float* __restrict__ dinv, float* __restrict__ xd,
                                 int N, int NB2) {
    __shared__ unsigned sdata[SCAP];
    __shared__ int hist[256];
    __shared__ int scn[256];
    __shared__ int bump[256];
    int tid = threadIdx.x;
    int b = blockIdx.x;
    int g0 = bbase[b], g1 = bbase[b + 1];
    int cnt = g1 - g0;
    bool fits = (cnt <= SCAP);
    if (tid < 256) hist[tid] = 0;
    __syncthreads();
    for (int i = tid; i < cnt; i += 512) {
        unsigned pk = bkt_data[g0 + i];
        if (fits) sdata[i] = pk;
        atomicAdd(&hist[pk >> 17], 1);
    }
    __syncthreads();
    int orig = (tid < 256) ? hist[tid] : 0;
    if (tid < 256) scn[tid] = orig;
    __syncthreads();
    for (int off = 1; off < 256; off <<= 1) {
        int w = (tid >= off && tid < 256) ? scn[tid - off] : 0;
        __syncthreads();
        if (tid < 256) scn[tid] += w;
        __syncthreads();
    }
    if (tid < 256) {
        int excl = scn[tid] - orig;
        bump[tid] = g0 + excl;
        int node = b * BSZ + tid;
        if (node < N) {
            float dv = rsqrtf((float)(orig + 1));
            dinv[node] = dv;
            xd[node] = x[node] * dv;
            e_start[node] = g0 + excl;
        }
    }
    if (b == NB2 - 1 && tid == 0) e_start[N] = g1;
    __syncthreads();
    for (int i = tid; i < cnt; i += 512) {
        unsigned pk = fits ? sdata[i] : bkt_data[g0 + i];
        int p = atomicAdd(&bump[pk >> 17], 1);
        csr[p] = pk & 0x1FFFFu;
    }
}

// ---------------- GCN layers: 4 threads per node (feature-quarter each) ----------------
// Intermediate rows: fp8 e4m3 [32] (32B) + f32 per-row scale -> 3.6 MB table, fits
// per-XCD L2 (4 MiB). sub = tid&3 owns features [sub*8, sub*8+8) = 8B quarter.
// Gather needs no shuffles (disjoint features); matmul exchanges v via quad-shuffles.

// o[0..7] += full 32-k matvec: o[f] = sum_k v[k] * W[k][sub*8+f], W row-major in LDS.
__device__ __forceinline__ void mm32_8(const float* __restrict__ sW, const float vr[8],
                                       int sub, int lane, float o[8]) {
    const float4* sW4 = (const float4*)sW;
    int base = lane & ~3;
#pragma unroll
    for (int r = 0; r < 4; r++) {
#pragma unroll
        for (int i = 0; i < 8; i++) {
            float vk = __shfl(vr[i], base | r, 64);
            int k = r * 8 + i;
            float4 w0 = sW4[k * 8 + sub * 2];
            float4 w1 = sW4[k * 8 + sub * 2 + 1];
            o[0] += vk * w0.x; o[1] += vk * w0.y; o[2] += vk * w0.z; o[3] += vk * w0.w;
            o[4] += vk * w1.x; o[5] += vk * w1.y; o[6] += vk * w1.z; o[7] += vk * w1.w;
        }
    }
}

// quantize o[8] (pre-scaled) to fp8 quarter + store; rm reduced across quad.
__device__ __forceinline__ void store_f8(unsigned char* __restrict__ u8, float* __restrict__ uscale,
                                         int d, int sub, const float o[8]) {
    float am = 0.f;
#pragma unroll
    for (int i = 0; i < 8; i++) am = fmaxf(am, fabsf(o[i]));
    am = fmaxf(am, __shfl_xor(am, 1, 64));
    am = fmaxf(am, __shfl_xor(am, 2, 64));
    float rm = fmaxf(am, 1e-20f);
    float sc = 128.f / rm;
    unsigned w0 = 0, w1 = 0;
    w0 = __builtin_amdgcn_cvt_pk_fp8_f32(o[0] * sc, o[1] * sc, w0, false);
    w0 = __builtin_amdgcn_cvt_pk_fp8_f32(o[2] * sc, o[3] * sc, w0, true);
    w1 = __builtin_amdgcn_cvt_pk_fp8_f32(o[4] * sc, o[5] * sc, w1, false);
    w1 = __builtin_amdgcn_cvt_pk_fp8_f32(o[6] * sc, o[7] * sc, w1, true);
    uint2 st; st.x = w0; st.y = w1;
    ((uint2*)u8)[(size_t)d * 4 + sub] = st;
    if (sub == 0) uscale[d] = rm * (1.f / 128.f);
}

// agg1: rank-1 gather (scalar xd), strided over 4 subs + quad-reduce; then fused MLP.
__global__ void __launch_bounds__(256) agg1_kernel(
                            const float* __restrict__ xd, const int* __restrict__ e_start,
                            const unsigned* __restrict__ csr, const float* __restrict__ dinv,
                            const float* __restrict__ W1, const float* __restrict__ b1,
                            const float* __restrict__ W2,
                            unsigned char* __restrict__ u8o, float* __restrict__ uso, int n) {
    __shared__ float sW2[1024];
    __shared__ float sW1[32], sb1[32];
    for (int i = threadIdx.x; i < 1024; i += 256) sW2[i] = W2[i];
    if (threadIdx.x < 32) { sW1[threadIdx.x] = W1[threadIdx.x]; sb1[threadIdx.x] = b1[threadIdx.x]; }
    __syncthreads();
    int t = blockIdx.x * 256 + threadIdx.x;
    int d = t >> 2, sub = t & 3;
    int lane = threadIdx.x & 63;
    if (d >= n) return;
    int e0 = e_start[d];
    int cnt = e_start[d + 1] - e0;
    float s = 0.f;
    int j = sub;
    for (; j + 8 <= cnt; j += 8) {
        int i0 = (int)csr[e0 + j], i1 = (int)csr[e0 + j + 4];
        s += xd[i0]; s += xd[i1];
    }
    for (; j < cnt; j += 4) s += xd[(int)csr[e0 + j]];
    s += __shfl_xor(s, 1, 64);
    s += __shfl_xor(s, 2, 64);
    float dv = dinv[d];
    float tt = dv * (s + xd[d]);
    float vr[8];
#pragma unroll
    for (int i = 0; i < 8; i++) vr[i] = fmaxf(tt * sW1[sub * 8 + i] + sb1[sub * 8 + i], 0.f);
    float o[8];
#pragma unroll
    for (int i = 0; i < 8; i++) o[i] = 0.f;
    mm32_8(sW2, vr, sub, lane, o);
#pragma unroll
    for (int i = 0; i < 8; i++) o[i] *= dv;
    store_f8(u8o, uso, d, sub, o);
}

// shared fp8 gather: acc[8] = sum over neighbors+self of rs * fp8 quarter-row
__device__ __forceinline__ void gather_f8(const unsigned char* __restrict__ u8,
                                          const float* __restrict__ uscale,
                                          const unsigned* __restrict__ csr,
                                          int e0, int cnt, int d, int sub, float acc[8]) {
#pragma unroll
    for (int i = 0; i < 8; i++) acc[i] = 0.f;
    const uint2* rows = (const uint2*)u8;
    int j = 0;
    for (; j + 4 <= cnt; j += 4) {
        int i0 = (int)csr[e0 + j],     i1 = (int)csr[e0 + j + 1];
        int i2 = (int)csr[e0 + j + 2], i3 = (int)csr[e0 + j + 3];
        float r0 = uscale[i0], r1 = uscale[i1], r2 = uscale[i2], r3 = uscale[i3];
        uint2 q0 = rows[(size_t)i0 * 4 + sub];
        uint2 q1 = rows[(size_t)i1 * 4 + sub];
        uint2 q2 = rows[(size_t)i2 * 4 + sub];
        uint2 q3 = rows[(size_t)i3 * 4 + sub];
        f8acc(q0, r0, acc); f8acc(q1, r1, acc); f8acc(q2, r2, acc); f8acc(q3, r3, acc);
    }
    for (; j < cnt; j++) {
        int i0 = (int)csr[e0 + j];
        float r0 = uscale[i0];
        uint2 q0 = rows[(size_t)i0 * 4 + sub];
        f8acc(q0, r0, acc);
    }
    // self row
    float rs = uscale[d];
    uint2 qs = rows[(size_t)d * 4 + sub];
    f8acc(qs, rs, acc);
}

// agg2: gather fp8 rows; v=relu(dv*acc+b); out = fp8(dv*(v@W)) + scale.
__global__ void __launch_bounds__(256) agg2_kernel(
                            const unsigned char* __restrict__ u8, const float* __restrict__ uscale,
                            const int* __restrict__ e_start, const unsigned* __restrict__ csr,
                            const float* __restrict__ dinv, const float* __restrict__ bias,
                            const float* __restrict__ W,
                            unsigned char* __restrict__ o8, float* __restrict__ oscale, int n) {
    __shared__ float sW[1024];
    __shared__ float sb[32];
    for (int i = threadIdx.x; i < 1024; i += 256) sW[i] = W[i];
    if (threadIdx.x < 32) sb[threadIdx.x] = bias[threadIdx.x];
    __syncthreads();
    int t = blockIdx.x * 256 + threadIdx.x;
    int d = t >> 2, sub = t & 3;
    int lane = threadIdx.x & 63;
    if (d >= n) return;
    int e0 = e_start[d];
    int cnt = e_start[d + 1] - e0;
    float acc[8];
    gather_f8(u8, uscale, csr, e0, cnt, d, sub, acc);
    float dv = dinv[d];
    float vr[8];
#pragma unroll
    for (int i = 0; i < 8; i++) vr[i] = fmaxf(dv * acc[i] + sb[sub * 8 + i], 0.f);
    float o[8];
#pragma unroll
    for (int i = 0; i < 8; i++) o[i] = 0.f;
    mm32_8(sW, vr, sub, lane, o);
#pragma unroll
    for (int i = 0; i < 8; i++) o[i] *= dv;
    store_f8(o8, oscale, d, sub, o);
}

// agg3: v=relu(dv*acc+b3) -> hb (bf16 quarter); theta = PI*sigmoid(relu(v@Wt1+bt1)@Wt2+bt2).
__global__ void __launch_bounds__(256) agg3_kernel(
                            const unsigned char* __restrict__ u8, const float* __restrict__ uscale,
                            const int* __restrict__ e_start, const unsigned* __restrict__ csr,
                            const float* __restrict__ dinv, const float* __restrict__ bias,
                            const float* __restrict__ Wt1, const float* __restrict__ bt1,
                            const float* __restrict__ Wt2, const float* __restrict__ bt2,
                            unsigned short* __restrict__ hb, float* __restrict__ theta, int n) {
    __shared__ float sW[1024];
    __shared__ float sb[32], sbt[32], sw2[32];
    for (int i = threadIdx.x; i < 1024; i += 256) sW[i] = Wt1[i];
    if (threadIdx.x < 32) {
        sb[threadIdx.x] = bias[threadIdx.x];
        sbt[threadIdx.x] = bt1[threadIdx.x];
        sw2[threadIdx.x] = Wt2[threadIdx.x];
    }
    __syncthreads();
    int t = blockIdx.x * 256 + threadIdx.x;
    int d = t >> 2, sub = t & 3;
    int lane = threadIdx.x & 63;
    if (d >= n) return;
    int e0 = e_start[d];
    int cnt = e_start[d + 1] - e0;
    float acc[8];
    gather_f8(u8, uscale, csr, e0, cnt, d, sub, acc);
    float dv = dinv[d];
    float vr[8];
#pragma unroll
    for (int i = 0; i < 8; i++) vr[i] = fmaxf(dv * acc[i] + sb[sub * 8 + i], 0.f);
    unsigned ow[4];
#pragma unroll
    for (int i2 = 0; i2 < 4; i2++) ow[i2] = bfpack(vr[2 * i2], vr[2 * i2 + 1]);
    ((uint4*)hb)[(size_t)d * 4 + sub] = *(uint4*)&ow[0];
    float o[8];
#pragma unroll
    for (int i = 0; i < 8; i++) o[i] = 0.f;
    mm32_8(sW, vr, sub, lane, o);
    float tl = 0.f;
#pragma unroll
    for (int i = 0; i < 8; i++)
        tl += fmaxf(o[i] + sbt[sub * 8 + i], 0.f) * sw2[sub * 8 + i];
    tl += __shfl_xor(tl, 1, 64);
    tl += __shfl_xor(tl, 2, 64);
    if (sub == 0) theta[d] = PI_F / (1.f + __expf(-(tl + bt2[0])));
}

// ---------------- pooled head: boundary index + block-per-graph reduce ----------------

__global__ void gb_kernel(const int* __restrict__ batch, int* __restrict__ gstart,
                          int n, int G) {
    int i = blockIdx.x * 256 + threadIdx.x;
    if (i >= n) return;
    int g = batch[i];
    if (i == 0) {
        for (int gg = 0; gg <= g; gg++) gstart[gg] = 0;
    } else {
        int gp = batch[i - 1];
        for (int gg = gp + 1; gg <= g; gg++) gstart[gg] = i;
    }
    if (i == n - 1) {
        for (int gg = g + 1; gg <= G; gg++) gstart[gg] = n;
    }
}

__global__ void __launch_bounds__(512) bg_kernel(
                          const unsigned short* __restrict__ hb, const int* __restrict__ gstart,
                          const float* __restrict__ Wg1, const float* __restrict__ bg1v,
                          const float* __restrict__ Wg2, const float* __restrict__ bg2v,
                          float* __restrict__ out, int G) {
    __shared__ float sW[1024];
    __shared__ float part[8][32];
    for (int i = threadIdx.x; i < 1024; i += 512) sW[i] = Wg1[i];
    int g = blockIdx.x;
    int s = gstart[g], e = gstart[g + 1];
    int w = threadIdx.x >> 6;
    int lane = threadIdx.x & 63;
    int f = lane & 31, h = lane >> 5;
    float a = 0.f;
    for (int i = s + (w << 1) + h; i < e; i += 16)
        a += __uint_as_float((unsigned)hb[((size_t)i << 5) + f] << 16);
    a += __shfl_xor(a, 32, 64);
    if (h == 0) part[w][f] = a;
    __syncthreads();
    if (w == 0) {
        float hv = 0.f;
#pragma unroll
        for (int p = 0; p < 8; p++) hv += part[p][f];
        hv /= fmaxf((float)(e - s), 1.f);
        int base = lane & 32;
        float acc = bg1v[f];
#pragma unroll
        for (int k = 0; k < 32; k++) acc += __shfl(hv, base | k, 64) * sW[k * 32 + f];
        acc = fmaxf(acc, 0.f);
        float p0 = acc * Wg2[f * 2 + 0];
        float p1 = acc * Wg2[f * 2 + 1];
#pragma unroll
        for (int m = 1; m < 32; m <<= 1) {
            p0 += __shfl_xor(p0, m, 64);
            p1 += __shfl_xor(p1, m, 64);
        }
        if (lane == 0) {
            out[g * 2 + 0] = 2.f * PI_F / (1.f + __expf(-(p0 + bg2v[0])));
            out[g * 2 + 1] = 2.f * PI_F / (1.f + __expf(-(p1 + bg2v[1])));
        }
    }
}

// ---------------- launch ----------------

extern "C" void kernel_launch(void* const* d_in, const int* in_sizes, int n_in,
                              void* d_out, int out_size, void* d_ws, size_t ws_size,
                              hipStream_t stream) {
    const float* x   = (const float*)d_in[0];
    const int*   ei  = (const int*)d_in[1];
    const int* batch = (const int*)d_in[2];
    const float* W1  = (const float*)d_in[3];
    const float* b1  = (const float*)d_in[4];
    const float* W2  = (const float*)d_in[5];
    const float* b2  = (const float*)d_in[6];
    const float* W3  = (const float*)d_in[7];
    const float* b3  = (const float*)d_in[8];
    const float* Wt1 = (const float*)d_in[9];
    const float* bt1 = (const float*)d_in[10];
    const float* Wt2 = (const float*)d_in[11];
    const float* bt2 = (const float*)d_in[12];
    const float* Wg1 = (const float*)d_in[13];
    const float* bg1 = (const float*)d_in[14];
    const float* Wg2 = (const float*)d_in[15];
    const float* bg2 = (const float*)d_in[16];

    const int N = in_sizes[0];
    const int E = in_sizes[1] / 2;
    const int G = 128;
    const int* src = ei;
    const int* dst = ei + E;
    float* theta_out = (float*)d_out;
    float* bg_out = (float*)d_out + N;

    const int NB2 = (N + BSZ - 1) >> BSH;
    const int CHUNK = (E + NBLK - 1) / NBLK;

    char* w = (char*)d_ws;
    auto alloc = [&](size_t bytes) -> char* { char* p = w; w += align256(bytes); return p; };
    int*      C        = (int*)alloc((size_t)NBLK * NB2 * 4);
    int*      colsum   = (int*)alloc((size_t)NB2 * 4);
    int*      bbase    = (int*)alloc((size_t)(NB2 + 1) * 4);
    unsigned* bkt_data = (unsigned*)alloc((size_t)E * 4);
    unsigned* csr      = (unsigned*)alloc((size_t)E * 4);
    int*      e_start  = (int*)alloc((size_t)(N + 1) * 4);
    float*    dinv     = (float*)alloc((size_t)N * 4);
    float*    xd       = (float*)alloc((size_t)N * 4);
    unsigned char* u2  = (unsigned char*)alloc((size_t)N * 32);
    float*    us2      = (float*)alloc((size_t)N * 4);
    unsigned char* u3  = (unsigned char*)alloc((size_t)N * 32);
    float*    us3      = (float*)alloc((size_t)N * 4);
    unsigned short* hb = (unsigned short*)alloc((size_t)N * 64);
    int*      gstart   = (int*)alloc((size_t)(G + 1) * 4);

    size_t ldsB = (size_t)NB2 * 4;
    count_kernel<<<NBLK, 1024, ldsB, stream>>>(dst, C, E, CHUNK, NB2);
    scan_blocks_kernel<<<NB2, 256, 0, stream>>>(C, colsum, NB2);
    scan_totals_kernel<<<1, 256, 0, stream>>>(colsum, bbase, NB2, E);
    scatter_kernel<<<NBLK, 1024, ldsB, stream>>>(src, dst, C, bbase, bkt_data, E, CHUNK, NB2);
    csr_build_kernel<<<NB2, 512, 0, stream>>>(bkt_data, bbase, x, csr, e_start, dinv, xd, N, NB2);
    gb_kernel<<<(N + 255) / 256, 256, 0, stream>>>(batch, gstart, N, G);

    unsigned gridQ = (unsigned)(((size_t)N * 4 + 255) / 256);   // 4 threads per node

    agg1_kernel<<<gridQ, 256, 0, stream>>>(xd, e_start, csr, dinv, W1, b1, W2, u2, us2, N);
    agg2_kernel<<<gridQ, 256, 0, stream>>>(u2, us2, e_start, csr, dinv, b2, W3, u3, us3, N);
    agg3_kernel<<<gridQ, 256, 0, stream>>>(u3, us3, e_start, csr, dinv, b3,
                                           Wt1, bt1, Wt2, bt2, hb, theta_out, N);

    bg_kernel<<<G, 512, 0, stream>>>(hb, gstart, Wg1, bg1, Wg2, bg2, bg_out, G);
}

// Round 10
// 282.246 us; speedup vs baseline: 2.9045x; 1.0198x over previous
//
#include <hip/hip_runtime.h>
#include <hip/hip_bf16.h>

#define PI_F 3.14159265358979323846f
#define NBLK 256     // chunk count for count/scatter passes (scan width)
#define BSH 8        // coarse bucket = 256 dst nodes
#define BSZ 256      // nodes per bucket
#define SCAP 10240   // LDS edge staging capacity (mean 8192, +22 sigma)
#define SLDS 3072    // per-block csr staging for agg kernels (64 nodes, mean 2048, +22 sigma)

static inline size_t align256(size_t x) { return (x + 255) & ~size_t(255); }

typedef float v2f __attribute__((ext_vector_type(2)));
typedef unsigned uvec4 __attribute__((ext_vector_type(4)));   // native vector: NT-store legal

// bf16 helpers (bit tricks; round-to-nearest via +0x8000)
__device__ __forceinline__ unsigned bfpack(float a, float b) {
    unsigned lo = (__float_as_uint(a) + 0x8000u) >> 16;
    unsigned hi = (__float_as_uint(b) + 0x8000u) & 0xFFFF0000u;
    return lo | hi;
}

// accumulate one 8B fp8 row-quarter (8 features) scaled by rs into acc[8]
__device__ __forceinline__ void f8acc(uint2 q, float rs, float acc[8]) {
    v2f l0 = __builtin_amdgcn_cvt_pk_f32_fp8(q.x, false);
    v2f h0 = __builtin_amdgcn_cvt_pk_f32_fp8(q.x, true);
    v2f l1 = __builtin_amdgcn_cvt_pk_f32_fp8(q.y, false);
    v2f h1 = __builtin_amdgcn_cvt_pk_f32_fp8(q.y, true);
    acc[0] += rs * l0.x; acc[1] += rs * l0.y; acc[2] += rs * h0.x; acc[3] += rs * h0.y;
    acc[4] += rs * l1.x; acc[5] += rs * l1.y; acc[6] += rs * h1.x; acc[7] += rs * h1.y;
}

// ---------------- atomic-free bucketed CSR build ----------------

__global__ void __launch_bounds__(1024) count_kernel(
                             const int* __restrict__ dst, int* __restrict__ C,
                             int E, int CHUNK, int NB2) {
    extern __shared__ int hist[];   // NB2 ints
    for (int i = threadIdx.x; i < NB2; i += 1024) hist[i] = 0;
    __syncthreads();
    int s0 = blockIdx.x * CHUNK, s1 = min(s0 + CHUNK, E);
    for (int e = s0 + threadIdx.x; e < s1; e += 1024)
        atomicAdd(&hist[dst[e] >> BSH], 1);
    __syncthreads();
    for (int i = threadIdx.x; i < NB2; i += 1024)
        C[(size_t)blockIdx.x * NB2 + i] = hist[i];
}

__global__ void scan_blocks_kernel(int* __restrict__ C, int* __restrict__ colsum, int NB2) {
    __shared__ int s[256];
    int k = blockIdx.x;
    int b = threadIdx.x;
    int v = C[(size_t)b * NB2 + k];
    s[b] = v;
    __syncthreads();
    for (int off = 1; off < 256; off <<= 1) {
        int w = (b >= off) ? s[b - off] : 0;
        __syncthreads();
        s[b] += w;
        __syncthreads();
    }
    C[(size_t)b * NB2 + k] = s[b] - v;   // exclusive
    if (b == 255) colsum[k] = s[255];
}

__global__ void scan_totals_kernel(const int* __restrict__ colsum, int* __restrict__ bbase,
                                   int NB2, int E) {
    __shared__ int s[256];
    __shared__ int running;
    if (threadIdx.x == 0) running = 0;
    __syncthreads();
    for (int base = 0; base < NB2; base += 256) {
        int i = base + threadIdx.x;
        int v = (i < NB2) ? colsum[i] : 0;
        s[threadIdx.x] = v;
        __syncthreads();
        for (int off = 1; off < 256; off <<= 1) {
            int w = (threadIdx.x >= (unsigned)off) ? s[threadIdx.x - off] : 0;
            __syncthreads();
            s[threadIdx.x] += w;
            __syncthreads();
        }
        if (i < NB2) bbase[i] = running + s[threadIdx.x] - v;
        __syncthreads();
        if (threadIdx.x == 255) running += s[255];
        __syncthreads();
    }
    if (threadIdx.x == 0) bbase[NB2] = E;
}

__global__ void __launch_bounds__(1024) scatter_kernel(
                               const int* __restrict__ src, const int* __restrict__ dst,
                               const int* __restrict__ C, const int* __restrict__ bbase,
                               unsigned* __restrict__ bkt_data, int E, int CHUNK, int NB2) {
    extern __shared__ int ofs[];   // NB2 ints
    for (int i = threadIdx.x; i < NB2; i += 1024)
        ofs[i] = bbase[i] + C[(size_t)blockIdx.x * NB2 + i];
    __syncthreads();
    int s0 = blockIdx.x * CHUNK, s1 = min(s0 + CHUNK, E);
    for (int e = s0 + threadIdx.x; e < s1; e += 1024) {
        int d = dst[e];
        int p = atomicAdd(&ofs[d >> BSH], 1);   // LDS atomic only
        bkt_data[p] = ((unsigned)(d & (BSZ - 1)) << 17) | (unsigned)src[e];
    }
}

__global__ void __launch_bounds__(512) csr_build_kernel(
                                 const unsigned* __restrict__ bkt_data, const int* __restrict__ bbase,
                                 const float* __restrict__ x,
                                 unsigned* __restrict__ csr, int* __restrict__ e_start,
                                 float* __restrict__ dinv, float* __restrict__ xd,
                                 int N, int NB2) {
    __shared__ unsigned sdata[SCAP];
    __shared__ int hist[256];
    __shared__ int scn[256];
    __shared__ int bump[256];
    int tid = threadIdx.x;
    int b = blockIdx.x;
    int g0 = bbase[b], g1 = bbase[b + 1];
    int cnt = g1 - g0;
    bool fits = (cnt <= SCAP);
    if (tid < 256) hist[tid] = 0;
    __syncthreads();
    for (int i = tid; i < cnt; i += 512) {
        unsigned pk = bkt_data[g0 + i];
        if (fits) sdata[i] = pk;
        atomicAdd(&hist[pk >> 17], 1);
    }
    __syncthreads();
    int orig = (tid < 256) ? hist[tid] : 0;
    if (tid < 256) scn[tid] = orig;
    __syncthreads();
    for (int off = 1; off < 256; off <<= 1) {
        int w = (tid >= off && tid < 256) ? scn[tid - off] : 0;
        __syncthreads();
        if (tid < 256) scn[tid] += w;
        __syncthreads();
    }
    if (tid < 256) {
        int excl = scn[tid] - orig;
        bump[tid] = g0 + excl;
        int node = b * BSZ + tid;
        if (node < N) {
            float dv = rsqrtf((float)(orig + 1));
            dinv[node] = dv;
            xd[node] = x[node] * dv;
            e_start[node] = g0 + excl;
        }
    }
    if (b == NB2 - 1 && tid == 0) e_start[N] = g1;
    __syncthreads();
    for (int i = tid; i < cnt; i += 512) {
        unsigned pk = fits ? sdata[i] : bkt_data[g0 + i];
        int p = atomicAdd(&bump[pk >> 17], 1);
        csr[p] = pk & 0x1FFFFu;
    }
}

// ---------------- GCN layers: 4 threads per node (feature-quarter each) ----------------
// Intermediate rows: fp8 e4m3 [32] (32B) + f32 per-row scale -> 3.6 MB table, fits
// per-XCD L2. Block = 64 nodes; their csr slice is contiguous -> staged into LDS via
// one coalesced NT sweep. Inner loop: 8 independent scale+row gathers in flight.

// o[0..7] += full 32-k matvec: o[f] = sum_k v[k] * W[k][sub*8+f], W row-major in LDS.
__device__ __forceinline__ void mm32_8(const float* __restrict__ sW, const float vr[8],
                                       int sub, int lane, float o[8]) {
    const float4* sW4 = (const float4*)sW;
    int base = lane & ~3;
#pragma unroll
    for (int r = 0; r < 4; r++) {
#pragma unroll
        for (int i = 0; i < 8; i++) {
            float vk = __shfl(vr[i], base | r, 64);
            int k = r * 8 + i;
            float4 w0 = sW4[k * 8 + sub * 2];
            float4 w1 = sW4[k * 8 + sub * 2 + 1];
            o[0] += vk * w0.x; o[1] += vk * w0.y; o[2] += vk * w0.z; o[3] += vk * w0.w;
            o[4] += vk * w1.x; o[5] += vk * w1.y; o[6] += vk * w1.z; o[7] += vk * w1.w;
        }
    }
}

// quantize o[8] (pre-scaled) to fp8 quarter + store; rm reduced across quad.
__device__ __forceinline__ void store_f8(unsigned char* __restrict__ u8, float* __restrict__ uscale,
                                         int d, int sub, const float o[8]) {
    float am = 0.f;
#pragma unroll
    for (int i = 0; i < 8; i++) am = fmaxf(am, fabsf(o[i]));
    am = fmaxf(am, __shfl_xor(am, 1, 64));
    am = fmaxf(am, __shfl_xor(am, 2, 64));
    float rm = fmaxf(am, 1e-20f);
    float sc = 128.f / rm;
    unsigned w0 = 0, w1 = 0;
    w0 = __builtin_amdgcn_cvt_pk_fp8_f32(o[0] * sc, o[1] * sc, w0, false);
    w0 = __builtin_amdgcn_cvt_pk_fp8_f32(o[2] * sc, o[3] * sc, w0, true);
    w1 = __builtin_amdgcn_cvt_pk_fp8_f32(o[4] * sc, o[5] * sc, w1, false);
    w1 = __builtin_amdgcn_cvt_pk_fp8_f32(o[6] * sc, o[7] * sc, w1, true);
    uint2 st; st.x = w0; st.y = w1;
    ((uint2*)u8)[(size_t)d * 4 + sub] = st;
    if (sub == 0) uscale[d] = rm * (1.f / 128.f);
}

// stage this block's contiguous csr slice into LDS (NT load); returns fits flag.
__device__ __forceinline__ bool stage_csr(const unsigned* __restrict__ csr,
                                          const int* __restrict__ e_start,
                                          int d0, int dEnd, int* sidx, int& E0) {
    E0 = e_start[d0];
    int E1 = e_start[dEnd];
    int m = E1 - E0;
    bool fits = (m <= SLDS);
    if (fits) {
        for (int i = threadIdx.x; i < m; i += 256)
            sidx[i] = (int)__builtin_nontemporal_load(&csr[E0 + i]);
    }
    __syncthreads();
    return fits;
}

// agg1: rank-1 gather (scalar xd), strided over 4 subs + quad-reduce; then fused MLP.
__global__ void __launch_bounds__(256) agg1_kernel(
                            const float* __restrict__ xd, const int* __restrict__ e_start,
                            const unsigned* __restrict__ csr, const float* __restrict__ dinv,
                            const float* __restrict__ W1, const float* __restrict__ b1,
                            const float* __restrict__ W2,
                            unsigned char* __restrict__ u8o, float* __restrict__ uso, int n) {
    __shared__ float sW2[1024];
    __shared__ float sW1[32], sb1[32];
    __shared__ int sidx[SLDS];
    for (int i = threadIdx.x; i < 1024; i += 256) sW2[i] = W2[i];
    if (threadIdx.x < 32) { sW1[threadIdx.x] = W1[threadIdx.x]; sb1[threadIdx.x] = b1[threadIdx.x]; }
    int d0 = blockIdx.x * 64;
    int dEnd = min(d0 + 64, n);
    int E0;
    bool fits = stage_csr(csr, e_start, d0, dEnd, sidx, E0);
    int d = d0 + (threadIdx.x >> 2), sub = threadIdx.x & 3;
    int lane = threadIdx.x & 63;
    if (d >= n) return;
    int e0 = e_start[d];
    int cnt = e_start[d + 1] - e0;
    int l0 = e0 - E0;
    float s = 0.f;
    int j = sub;
    if (fits) {
        for (; j < cnt; j += 4) s += xd[sidx[l0 + j]];
    } else {
        for (; j < cnt; j += 4) s += xd[(int)csr[e0 + j]];
    }
    s += __shfl_xor(s, 1, 64);
    s += __shfl_xor(s, 2, 64);
    float dv = dinv[d];
    float tt = dv * (s + xd[d]);
    float vr[8];
#pragma unroll
    for (int i = 0; i < 8; i++) vr[i] = fmaxf(tt * sW1[sub * 8 + i] + sb1[sub * 8 + i], 0.f);
    float o[8];
#pragma unroll
    for (int i = 0; i < 8; i++) o[i] = 0.f;
    mm32_8(sW2, vr, sub, lane, o);
#pragma unroll
    for (int i = 0; i < 8; i++) o[i] *= dv;
    store_f8(u8o, uso, d, sub, o);
}

// shared fp8 gather with LDS-staged indices: 8 scale + 8 row gathers in flight.
__device__ __forceinline__ void gather_f8(const unsigned char* __restrict__ u8,
                                          const float* __restrict__ uscale,
                                          const int* __restrict__ sidx, bool fits,
                                          const unsigned* __restrict__ csr,
                                          int e0, int l0, int cnt, int d, int sub, float acc[8]) {
#pragma unroll
    for (int i = 0; i < 8; i++) acc[i] = 0.f;
    const uint2* rows = (const uint2*)u8;
    int j = 0;
    if (fits) {
        for (; j + 8 <= cnt; j += 8) {
            int id[8];
#pragma unroll
            for (int k = 0; k < 8; k++) id[k] = sidx[l0 + j + k];
            float rs[8];
#pragma unroll
            for (int k = 0; k < 8; k++) rs[k] = uscale[id[k]];
            uint2 q[8];
#pragma unroll
            for (int k = 0; k < 8; k++) q[k] = rows[(size_t)id[k] * 4 + sub];
#pragma unroll
            for (int k = 0; k < 8; k++) f8acc(q[k], rs[k], acc);
        }
        for (; j < cnt; j++) {
            int i0 = sidx[l0 + j];
            f8acc(rows[(size_t)i0 * 4 + sub], uscale[i0], acc);
        }
    } else {
        for (; j + 4 <= cnt; j += 4) {
            int i0 = (int)csr[e0 + j],     i1 = (int)csr[e0 + j + 1];
            int i2 = (int)csr[e0 + j + 2], i3 = (int)csr[e0 + j + 3];
            float r0 = uscale[i0], r1 = uscale[i1], r2 = uscale[i2], r3 = uscale[i3];
            uint2 q0 = rows[(size_t)i0 * 4 + sub];
            uint2 q1 = rows[(size_t)i1 * 4 + sub];
            uint2 q2 = rows[(size_t)i2 * 4 + sub];
            uint2 q3 = rows[(size_t)i3 * 4 + sub];
            f8acc(q0, r0, acc); f8acc(q1, r1, acc); f8acc(q2, r2, acc); f8acc(q3, r3, acc);
        }
        for (; j < cnt; j++) {
            int i0 = (int)csr[e0 + j];
            f8acc(rows[(size_t)i0 * 4 + sub], uscale[i0], acc);
        }
    }
    // self row
    f8acc(rows[(size_t)d * 4 + sub], uscale[d], acc);
}

// agg2: gather fp8 rows; v=relu(dv*acc+b); out = fp8(dv*(v@W)) + scale.
__global__ void __launch_bounds__(256) agg2_kernel(
                            const unsigned char* __restrict__ u8, const float* __restrict__ uscale,
                            const int* __restrict__ e_start, const unsigned* __restrict__ csr,
                            const float* __restrict__ dinv, const float* __restrict__ bias,
                            const float* __restrict__ W,
                            unsigned char* __restrict__ o8, float* __restrict__ oscale, int n) {
    __shared__ float sW[1024];
    __shared__ float sb[32];
    __shared__ int sidx[SLDS];
    for (int i = threadIdx.x; i < 1024; i += 256) sW[i] = W[i];
    if (threadIdx.x < 32) sb[threadIdx.x] = bias[threadIdx.x];
    int d0 = blockIdx.x * 64;
    int dEnd = min(d0 + 64, n);
    int E0;
    bool fits = stage_csr(csr, e_start, d0, dEnd, sidx, E0);
    int d = d0 + (threadIdx.x >> 2), sub = threadIdx.x & 3;
    int lane = threadIdx.x & 63;
    if (d >= n) return;
    int e0 = e_start[d];
    int cnt = e_start[d + 1] - e0;
    float acc[8];
    gather_f8(u8, uscale, sidx, fits, csr, e0, e0 - E0, cnt, d, sub, acc);
    float dv = dinv[d];
    float vr[8];
#pragma unroll
    for (int i = 0; i < 8; i++) vr[i] = fmaxf(dv * acc[i] + sb[sub * 8 + i], 0.f);
    float o[8];
#pragma unroll
    for (int i = 0; i < 8; i++) o[i] = 0.f;
    mm32_8(sW, vr, sub, lane, o);
#pragma unroll
    for (int i = 0; i < 8; i++) o[i] *= dv;
    store_f8(o8, oscale, d, sub, o);
}

// agg3: v=relu(dv*acc+b3) -> hb (bf16 quarter, NT); theta head (NT store).
__global__ void __launch_bounds__(256) agg3_kernel(
                            const unsigned char* __restrict__ u8, const float* __restrict__ uscale,
                            const int* __restrict__ e_start, const unsigned* __restrict__ csr,
                            const float* __restrict__ dinv, const float* __restrict__ bias,
                            const float* __restrict__ Wt1, const float* __restrict__ bt1,
                            const float* __restrict__ Wt2, const float* __restrict__ bt2,
                            unsigned short* __restrict__ hb, float* __restrict__ theta, int n) {
    __shared__ float sW[1024];
    __shared__ float sb[32], sbt[32], sw2[32];
    __shared__ int sidx[SLDS];
    for (int i = threadIdx.x; i < 1024; i += 256) sW[i] = Wt1[i];
    if (threadIdx.x < 32) {
        sb[threadIdx.x] = bias[threadIdx.x];
        sbt[threadIdx.x] = bt1[threadIdx.x];
        sw2[threadIdx.x] = Wt2[threadIdx.x];
    }
    int d0 = blockIdx.x * 64;
    int dEnd = min(d0 + 64, n);
    int E0;
    bool fits = stage_csr(csr, e_start, d0, dEnd, sidx, E0);
    int d = d0 + (threadIdx.x >> 2), sub = threadIdx.x & 3;
    int lane = threadIdx.x & 63;
    if (d >= n) return;
    int e0 = e_start[d];
    int cnt = e_start[d + 1] - e0;
    float acc[8];
    gather_f8(u8, uscale, sidx, fits, csr, e0, e0 - E0, cnt, d, sub, acc);
    float dv = dinv[d];
    float vr[8];
#pragma unroll
    for (int i = 0; i < 8; i++) vr[i] = fmaxf(dv * acc[i] + sb[sub * 8 + i], 0.f);
    uvec4 st;
    st.x = bfpack(vr[0], vr[1]);
    st.y = bfpack(vr[2], vr[3]);
    st.z = bfpack(vr[4], vr[5]);
    st.w = bfpack(vr[6], vr[7]);
    __builtin_nontemporal_store(st, (uvec4*)hb + (size_t)d * 4 + sub);
    float o[8];
#pragma unroll
    for (int i = 0; i < 8; i++) o[i] = 0.f;
    mm32_8(sW, vr, sub, lane, o);
    float tl = 0.f;
#pragma unroll
    for (int i = 0; i < 8; i++)
        tl += fmaxf(o[i] + sbt[sub * 8 + i], 0.f) * sw2[sub * 8 + i];
    tl += __shfl_xor(tl, 1, 64);
    tl += __shfl_xor(tl, 2, 64);
    if (sub == 0) __builtin_nontemporal_store(PI_F / (1.f + __expf(-(tl + bt2[0]))), theta + d);
}

// ---------------- pooled head: boundary index + block-per-graph reduce ----------------

__global__ void gb_kernel(const int* __restrict__ batch, int* __restrict__ gstart,
                          int n, int G) {
    int i = blockIdx.x * 256 + threadIdx.x;
    if (i >= n) return;
    int g = batch[i];
    if (i == 0) {
        for (int gg = 0; gg <= g; gg++) gstart[gg] = 0;
    } else {
        int gp = batch[i - 1];
        for (int gg = gp + 1; gg <= g; gg++) gstart[gg] = i;
    }
    if (i == n - 1) {
        for (int gg = g + 1; gg <= G; gg++) gstart[gg] = n;
    }
}

__global__ void __launch_bounds__(512) bg_kernel(
                          const unsigned short* __restrict__ hb, const int* __restrict__ gstart,
                          const float* __restrict__ Wg1, const float* __restrict__ bg1v,
                          const float* __restrict__ Wg2, const float* __restrict__ bg2v,
                          float* __restrict__ out, int G) {
    __shared__ float sW[1024];
    __shared__ float part[8][32];
    for (int i = threadIdx.x; i < 1024; i += 512) sW[i] = Wg1[i];
    int g = blockIdx.x;
    int s = gstart[g], e = gstart[g + 1];
    int w = threadIdx.x >> 6;
    int lane = threadIdx.x & 63;
    int f = lane & 31, h = lane >> 5;
    float a = 0.f;
    for (int i = s + (w << 1) + h; i < e; i += 16)
        a += __uint_as_float((unsigned)hb[((size_t)i << 5) + f] << 16);
    a += __shfl_xor(a, 32, 64);
    if (h == 0) part[w][f] = a;
    __syncthreads();
    if (w == 0) {
        float hv = 0.f;
#pragma unroll
        for (int p = 0; p < 8; p++) hv += part[p][f];
        hv /= fmaxf((float)(e - s), 1.f);
        int base = lane & 32;
        float acc = bg1v[f];
#pragma unroll
        for (int k = 0; k < 32; k++) acc += __shfl(hv, base | k, 64) * sW[k * 32 + f];
        acc = fmaxf(acc, 0.f);
        float p0 = acc * Wg2[f * 2 + 0];
        float p1 = acc * Wg2[f * 2 + 1];
#pragma unroll
        for (int m = 1; m < 32; m <<= 1) {
            p0 += __shfl_xor(p0, m, 64);
            p1 += __shfl_xor(p1, m, 64);
        }
        if (lane == 0) {
            out[g * 2 + 0] = 2.f * PI_F / (1.f + __expf(-(p0 + bg2v[0])));
            out[g * 2 + 1] = 2.f * PI_F / (1.f + __expf(-(p1 + bg2v[1])));
        }
    }
}

// ---------------- launch ----------------

extern "C" void kernel_launch(void* const* d_in, const int* in_sizes, int n_in,
                              void* d_out, int out_size, void* d_ws, size_t ws_size,
                              hipStream_t stream) {
    const float* x   = (const float*)d_in[0];
    const int*   ei  = (const int*)d_in[1];
    const int* batch = (const int*)d_in[2];
    const float* W1  = (const float*)d_in[3];
    const float* b1  = (const float*)d_in[4];
    const float* W2  = (const float*)d_in[5];
    const float* b2  = (const float*)d_in[6];
    const float* W3  = (const float*)d_in[7];
    const float* b3  = (const float*)d_in[8];
    const float* Wt1 = (const float*)d_in[9];
    const float* bt1 = (const float*)d_in[10];
    const float* Wt2 = (const float*)d_in[11];
    const float* bt2 = (const float*)d_in[12];
    const float* Wg1 = (const float*)d_in[13];
    const float* bg1 = (const float*)d_in[14];
    const float* Wg2 = (const float*)d_in[15];
    const float* bg2 = (const float*)d_in[16];

    const int N = in_sizes[0];
    const int E = in_sizes[1] / 2;
    const int G = 128;
    const int* src = ei;
    const int* dst = ei + E;
    float* theta_out = (float*)d_out;
    float* bg_out = (float*)d_out + N;

    const int NB2 = (N + BSZ - 1) >> BSH;
    const int CHUNK = (E + NBLK - 1) / NBLK;

    char* w = (char*)d_ws;
    auto alloc = [&](size_t bytes) -> char* { char* p = w; w += align256(bytes); return p; };
    int*      C        = (int*)alloc((size_t)NBLK * NB2 * 4);
    int*      colsum   = (int*)alloc((size_t)NB2 * 4);
    int*      bbase    = (int*)alloc((size_t)(NB2 + 1) * 4);
    unsigned* bkt_data = (unsigned*)alloc((size_t)E * 4);
    unsigned* csr      = (unsigned*)alloc((size_t)E * 4);
    int*      e_start  = (int*)alloc((size_t)(N + 1) * 4);
    float*    dinv     = (float*)alloc((size_t)N * 4);
    float*    xd       = (float*)alloc((size_t)N * 4);
    unsigned char* u2  = (unsigned char*)alloc((size_t)N * 32);
    float*    us2      = (float*)alloc((size_t)N * 4);
    unsigned char* u3  = (unsigned char*)alloc((size_t)N * 32);
    float*    us3      = (float*)alloc((size_t)N * 4);
    unsigned short* hb = (unsigned short*)alloc((size_t)N * 64);
    int*      gstart   = (int*)alloc((size_t)(G + 1) * 4);

    size_t ldsB = (size_t)NB2 * 4;
    count_kernel<<<NBLK, 1024, ldsB, stream>>>(dst, C, E, CHUNK, NB2);
    scan_blocks_kernel<<<NB2, 256, 0, stream>>>(C, colsum, NB2);
    scan_totals_kernel<<<1, 256, 0, stream>>>(colsum, bbase, NB2, E);
    scatter_kernel<<<NBLK, 1024, ldsB, stream>>>(src, dst, C, bbase, bkt_data, E, CHUNK, NB2);
    csr_build_kernel<<<NB2, 512, 0, stream>>>(bkt_data, bbase, x, csr, e_start, dinv, xd, N, NB2);
    gb_kernel<<<(N + 255) / 256, 256, 0, stream>>>(batch, gstart, N, G);

    unsigned gridQ = (unsigned)(((size_t)N * 4 + 255) / 256);   // 4 threads per node

    agg1_kernel<<<gridQ, 256, 0, stream>>>(xd, e_start, csr, dinv, W1, b1, W2, u2, us2, N);
    agg2_kernel<<<gridQ, 256, 0, stream>>>(u2, us2, e_start, csr, dinv, b2, W3, u3, us3, N);
    agg3_kernel<<<gridQ, 256, 0, stream>>>(u3, us3, e_start, csr, dinv, b3,
                                           Wt1, bt1, Wt2, bt2, hb, theta_out, N);

    bg_kernel<<<G, 512, 0, stream>>>(hb, gstart, Wg1, bg1, Wg2, bg2, bg_out, G);
}